// Round 2
// baseline (10475.919 us; speedup 1.0000x reference)
//
#include <hip/hip_runtime.h>

#define NNODES 100000
#define NEDGES 1600000
#define NGRAPHS 2048
#define BN_EPS 1e-5f

// ---------------- copy (float4) ----------------
__global__ __launch_bounds__(256) void copy4_kernel(const float4* __restrict__ src,
                                                    float4* __restrict__ dst, int n4) {
    int i = blockIdx.x * 256 + threadIdx.x;
    if (i < n4) dst[i] = src[i];
}

// ---------------- edge scatter: agg[dst] += x[src] ----------------
template <int DIM, int CHUNK>
__global__ __launch_bounds__(256) void scatter_kernel(const float* __restrict__ x,
                                                      const int* __restrict__ srcA,
                                                      const int* __restrict__ dstA,
                                                      float* __restrict__ agg) {
    constexpr int PE = DIM / CHUNK;  // chunks per edge
    int gid = blockIdx.x * 256 + threadIdx.x;
    if (gid >= NEDGES * PE) return;
    int e = gid / PE;
    int c = gid - e * PE;
    int s = srcA[e];
    int d = dstA[e];
    const float* xp = x + (size_t)s * DIM + c * CHUNK;
    float* ap = agg + (size_t)d * DIM + c * CHUNK;
    if (CHUNK == 4) {
        float4 v = *(const float4*)xp;
        atomicAdd(ap + 0, v.x);
        atomicAdd(ap + 1, v.y);
        atomicAdd(ap + 2, v.z);
        atomicAdd(ap + 3, v.w);
    } else {
        float2 v = *(const float2*)xp;
        atomicAdd(ap + 0, v.x);
        atomicAdd(ap + 1, v.y);
    }
}

// ---------------- BN stats: per-column sum & sumsq ----------------
template <int N>
__global__ __launch_bounds__(256) void bnstats_kernel(const float* __restrict__ h,
                                                      float* __restrict__ sums) {
    constexpr int SHIFT = (N == 128) ? 7 : 8;
    int t = blockIdx.x * 256 + threadIdx.x;  // grid covers N*256 threads
    int col = t & (N - 1);
    int slice = t >> SHIFT;  // 0..255
    float s = 0.f, s2 = 0.f;
    for (int r = slice; r < NNODES; r += 256) {
        float v = h[(size_t)r * N + col];
        s += v;
        s2 += v * v;
    }
    atomicAdd(&sums[col], s);
    atomicAdd(&sums[N + col], s2);
}

__global__ void bnfinal_kernel(const float* __restrict__ sums, const float* __restrict__ gamma,
                               const float* __restrict__ beta, float* __restrict__ scale,
                               float* __restrict__ shift, int N, float invM) {
    int c = blockIdx.x * blockDim.x + threadIdx.x;
    if (c < N) {
        float mean = sums[c] * invM;
        float var = sums[N + c] * invM - mean * mean;
        float sc = gamma[c] * rsqrtf(var + BN_EPS);
        scale[c] = sc;
        shift[c] = beta[c] - mean * sc;
    }
}

// ---------------- tiled fp32 GEMM: C = op(A) @ W + bias ----------------
// A: MxK row-major, W: KxN row-major. BM=BN=64, BK=16, 256 threads, 4x4/thread.
// BNRELU_A: A element -> relu(A*scale[k]+shift[k]). RELU_OUT: relu epilogue.
template <bool BNRELU_A, bool RELU_OUT>
__global__ __launch_bounds__(256) void gemm_kernel(const float* __restrict__ A,
                                                   const float* __restrict__ W,
                                                   const float* __restrict__ bias,
                                                   const float* __restrict__ scale,
                                                   const float* __restrict__ shift,
                                                   float* __restrict__ C, int M, int K, int N) {
    __shared__ __align__(16) float As[16][68];  // [k][m], padded (272B rows keep f4 align)
    __shared__ __align__(16) float Bs[16][64];  // [k][n]
    const int tid = threadIdx.x;
    const int tx = tid & 15;
    const int ty = tid >> 4;
    const int m0 = blockIdx.x * 64;
    const int n0 = blockIdx.y * 64;

    float c[4][4] = {};

    for (int k0 = 0; k0 < K; k0 += 16) {
        // stage A tile (64 rows x 16 cols), transposed into As[k][m]
#pragma unroll
        for (int i = 0; i < 4; ++i) {
            int lin = tid + i * 256;
            int m = lin >> 4;
            int k = lin & 15;
            int gm = m0 + m;
            int gk = k0 + k;
            float v = 0.f;
            if (gm < M && gk < K) {
                v = A[(size_t)gm * K + gk];
                if (BNRELU_A) v = fmaxf(v * scale[gk] + shift[gk], 0.f);
            }
            As[k][m] = v;
        }
        // stage W tile (16 rows x 64 cols)
#pragma unroll
        for (int i = 0; i < 4; ++i) {
            int lin = tid + i * 256;
            int k = lin >> 6;
            int n = lin & 63;
            int gk = k0 + k;
            float v = 0.f;
            if (gk < K) v = W[(size_t)gk * N + n0 + n];
            Bs[k][n] = v;
        }
        __syncthreads();
#pragma unroll
        for (int kk = 0; kk < 16; ++kk) {
            float4 a = *(const float4*)&As[kk][ty * 4];
            float4 b = *(const float4*)&Bs[kk][tx * 4];
            c[0][0] += a.x * b.x; c[0][1] += a.x * b.y; c[0][2] += a.x * b.z; c[0][3] += a.x * b.w;
            c[1][0] += a.y * b.x; c[1][1] += a.y * b.y; c[1][2] += a.y * b.z; c[1][3] += a.y * b.w;
            c[2][0] += a.z * b.x; c[2][1] += a.z * b.y; c[2][2] += a.z * b.z; c[2][3] += a.z * b.w;
            c[3][0] += a.w * b.x; c[3][1] += a.w * b.y; c[3][2] += a.w * b.z; c[3][3] += a.w * b.w;
        }
        __syncthreads();
    }

#pragma unroll
    for (int i = 0; i < 4; ++i) {
        int gm = m0 + ty * 4 + i;
        if (gm >= M) continue;
#pragma unroll
        for (int j = 0; j < 4; ++j) {
            int gn = n0 + tx * 4 + j;
            float v = c[i][j] + bias[gn];
            if (RELU_OUT) v = fmaxf(v, 0.f);
            C[(size_t)gm * N + gn] = v;
        }
    }
}

// ---------------- global add pool: g[batch[n]] += h[n] ----------------
__global__ __launch_bounds__(256) void pool_kernel(const float* __restrict__ h,
                                                   const int* __restrict__ batch,
                                                   float* __restrict__ g) {
    int gid = blockIdx.x * 256 + threadIdx.x;  // node*32 + c4 (128/4)
    if (gid >= NNODES * 32) return;
    int node = gid >> 5;
    int c4 = gid & 31;
    int b = batch[node];
    float4 v = *(const float4*)&h[(size_t)node * 128 + c4 * 4];
    float* gp = &g[(size_t)b * 128 + c4 * 4];
    atomicAdd(gp + 0, v.x);
    atomicAdd(gp + 1, v.y);
    atomicAdd(gp + 2, v.z);
    atomicAdd(gp + 3, v.w);
}

extern "C" void kernel_launch(void* const* d_in, const int* in_sizes, int n_in, void* d_out,
                              int out_size, void* d_ws, size_t ws_size, hipStream_t stream) {
    const float* x = (const float*)d_in[0];
    const int* ei = (const int*)d_in[1];
    const int* batch = (const int*)d_in[2];
    const int* srcA = ei;
    const int* dstA = ei + NEDGES;

    const float* gw1[3] = {(const float*)d_in[3], (const float*)d_in[9], (const float*)d_in[15]};
    const float* gb1[3] = {(const float*)d_in[4], (const float*)d_in[10], (const float*)d_in[16]};
    const float* gga[3] = {(const float*)d_in[5], (const float*)d_in[11], (const float*)d_in[17]};
    const float* gbe[3] = {(const float*)d_in[6], (const float*)d_in[12], (const float*)d_in[18]};
    const float* gw2[3] = {(const float*)d_in[7], (const float*)d_in[13], (const float*)d_in[19]};
    const float* gb2[3] = {(const float*)d_in[8], (const float*)d_in[14], (const float*)d_in[20]};
    const float* fc0_w = (const float*)d_in[21];
    const float* fc0_b = (const float*)d_in[22];
    const float* fc1_w = (const float*)d_in[23];
    const float* fc1_b = (const float*)d_in[24];

    // --- workspace layout: only TWO N x 256 regions (rotation schedule) ---
    // L0: agg=R0, h1=R1, out=R0 | L1: agg=R1, h1=R0, out=R1 | L2: agg=R0, h1=R1, out=R0
    // Valid because: scatter reads xin/writes agg; GEMM1 reads agg/writes h1 (xin dead);
    // GEMM2 reads h1/writes out (agg dead). Total ws ~214 MB.
    float* ws = (float*)d_ws;
    const size_t BUF = (size_t)NNODES * 256;
    float* R0 = ws;
    float* R1 = R0 + BUF;
    float* stats = R1 + BUF;                // 2*256
    float* scsh = stats + 512;              // 2*256 (scale, shift)
    float* g = scsh + 512;                  // 2048*128 pooled
    float* gh = g + (size_t)NGRAPHS * 128;  // 2048*1024 fc hidden

    float* aggP[3] = {R0, R1, R0};
    float* h1P[3] = {R1, R0, R1};
    float* outP[3] = {R0, R1, R0};

    const int dims_in[3] = {66, 128, 256};
    const int dims_out[3] = {128, 256, 128};

    const float* xin = x;
    for (int L = 0; L < 3; ++L) {
        int din = dims_in[L];
        int dout = dims_out[L];
        float* agg = aggP[L];
        float* h1 = h1P[L];
        float* out = outP[L];
        // agg = xin
        int n4 = NNODES * din / 4;
        copy4_kernel<<<(n4 + 255) / 256, 256, 0, stream>>>((const float4*)xin, (float4*)agg, n4);
        // agg[dst] += xin[src]
        if (din == 66)
            scatter_kernel<66, 2><<<(NEDGES * 33 + 255) / 256, 256, 0, stream>>>(xin, srcA, dstA, agg);
        else if (din == 128)
            scatter_kernel<128, 4><<<(NEDGES * 32 + 255) / 256, 256, 0, stream>>>(xin, srcA, dstA, agg);
        else
            scatter_kernel<256, 4><<<(NEDGES * 64 + 255) / 256, 256, 0, stream>>>(xin, srcA, dstA, agg);
        // h1 = agg @ w1 + b1
        dim3 grid1((NNODES + 63) / 64, dout / 64);
        gemm_kernel<false, false><<<grid1, 256, 0, stream>>>(agg, gw1[L], gb1[L], nullptr, nullptr,
                                                             h1, NNODES, din, dout);
        // BN stats -> scale/shift
        hipMemsetAsync(stats, 0, 2 * dout * sizeof(float), stream);
        if (dout == 128)
            bnstats_kernel<128><<<128, 256, 0, stream>>>(h1, stats);
        else
            bnstats_kernel<256><<<256, 256, 0, stream>>>(h1, stats);
        bnfinal_kernel<<<1, dout, 0, stream>>>(stats, gga[L], gbe[L], scsh, scsh + dout, dout,
                                               1.0f / NNODES);
        // out = relu( relu(bn(h1)) @ w2 + b2 )
        dim3 grid2((NNODES + 63) / 64, dout / 64);
        gemm_kernel<true, true><<<grid2, 256, 0, stream>>>(h1, gw2[L], gb2[L], scsh, scsh + dout,
                                                           out, NNODES, dout, dout);
        xin = out;
    }

    // global add pool (output dim 128); final node features in outP[2]
    hipMemsetAsync(g, 0, (size_t)NGRAPHS * 128 * sizeof(float), stream);
    pool_kernel<<<(NNODES * 32 + 255) / 256, 256, 0, stream>>>(outP[2], batch, g);

    // fc0: relu(g @ fc0_w + fc0_b)  (2048x128 @ 128x1024)
    gemm_kernel<false, true><<<dim3(NGRAPHS / 64, 1024 / 64), 256, 0, stream>>>(
        g, fc0_w, fc0_b, nullptr, nullptr, gh, NGRAPHS, 128, 1024);
    // fc1: gh @ fc1_w + fc1_b  (2048x1024 @ 1024x128) -> d_out
    gemm_kernel<false, false><<<dim3(NGRAPHS / 64, 128 / 64), 256, 0, stream>>>(
        gh, fc1_w, fc1_b, nullptr, nullptr, (float*)d_out, NGRAPHS, 1024, 128);
}

// Round 3
// 2430.382 us; speedup vs baseline: 4.3104x; 4.3104x over previous
//
#include <hip/hip_runtime.h>

#define NNODES 100000
#define NEDGES 1600000
#define NGRAPHS 2048
#define BN_EPS 1e-5f

// ---------------- copy (float4) ----------------
__global__ __launch_bounds__(256) void copy4_kernel(const float4* __restrict__ src,
                                                    float4* __restrict__ dst, int n4) {
    int i = blockIdx.x * 256 + threadIdx.x;
    if (i < n4) dst[i] = src[i];
}

// ---------------- CSR build ----------------
__global__ __launch_bounds__(256) void deg_kernel(const int* __restrict__ dstA,
                                                  int* __restrict__ deg) {
    int e = blockIdx.x * 256 + threadIdx.x;
    if (e < NEDGES) atomicAdd(&deg[dstA[e]], 1);
}

// single-block exclusive scan over deg[0..NNODES) -> rowptr[0..NNODES], cursor copy
__global__ __launch_bounds__(1024) void scan_kernel(const int* __restrict__ deg,
                                                    int* __restrict__ rowptr,
                                                    int* __restrict__ cursor) {
    __shared__ int part[1024];
    const int t = threadIdx.x;
    const int CH = (NNODES + 1023) / 1024;  // 98
    int lo = t * CH;
    int hi = lo + CH;
    if (hi > NNODES) hi = NNODES;
    int s = 0;
    for (int i = lo; i < hi; ++i) s += deg[i];
    part[t] = s;
    __syncthreads();
    // Hillis-Steele inclusive scan
    for (int off = 1; off < 1024; off <<= 1) {
        int v = (t >= off) ? part[t - off] : 0;
        __syncthreads();
        part[t] += v;
        __syncthreads();
    }
    int run = (t == 0) ? 0 : part[t - 1];
    for (int i = lo; i < hi; ++i) {
        rowptr[i] = run;
        cursor[i] = run;
        run += deg[i];
    }
    if (t == 1023) rowptr[NNODES] = part[1023];
}

__global__ __launch_bounds__(256) void fill_kernel(const int* __restrict__ srcA,
                                                   const int* __restrict__ dstA,
                                                   int* __restrict__ cursor,
                                                   int* __restrict__ adj) {
    int e = blockIdx.x * 256 + threadIdx.x;
    if (e < NEDGES) {
        int d = dstA[e];
        int loc = atomicAdd(&cursor[d], 1);
        adj[loc] = srcA[e];
    }
}

// ---------------- gather aggregation: agg[n] = x[n] + sum_{s in adj[n]} x[s] ----------------
template <int DIM, int CHUNK>
__global__ __launch_bounds__(256) void gather_kernel(const float* __restrict__ x,
                                                     const int* __restrict__ rowptr,
                                                     const int* __restrict__ adj,
                                                     float* __restrict__ agg) {
    constexpr int PE = DIM / CHUNK;
    int gid = blockIdx.x * 256 + threadIdx.x;
    if (gid >= NNODES * PE) return;
    int node = gid / PE;
    int c = gid - node * PE;
    const int beg = rowptr[node];
    const int end = rowptr[node + 1];
    if (CHUNK == 4) {
        const float4* xp = (const float4*)x;
        float4 acc = xp[(size_t)node * PE + c];
        for (int i = beg; i < end; ++i) {
            int s = adj[i];
            float4 v = xp[(size_t)s * PE + c];
            acc.x += v.x;
            acc.y += v.y;
            acc.z += v.z;
            acc.w += v.w;
        }
        ((float4*)agg)[(size_t)node * PE + c] = acc;
    } else {
        const float2* xp = (const float2*)x;
        float2 acc = xp[(size_t)node * PE + c];
        for (int i = beg; i < end; ++i) {
            int s = adj[i];
            float2 v = xp[(size_t)s * PE + c];
            acc.x += v.x;
            acc.y += v.y;
        }
        ((float2*)agg)[(size_t)node * PE + c] = acc;
    }
}

// ---------------- BN stats: per-column sum & sumsq ----------------
template <int N>
__global__ __launch_bounds__(256) void bnstats_kernel(const float* __restrict__ h,
                                                      float* __restrict__ sums) {
    constexpr int SHIFT = (N == 128) ? 7 : 8;
    int t = blockIdx.x * 256 + threadIdx.x;  // grid covers N*256 threads
    int col = t & (N - 1);
    int slice = t >> SHIFT;  // 0..255
    float s = 0.f, s2 = 0.f;
    for (int r = slice; r < NNODES; r += 256) {
        float v = h[(size_t)r * N + col];
        s += v;
        s2 += v * v;
    }
    atomicAdd(&sums[col], s);
    atomicAdd(&sums[N + col], s2);
}

__global__ void bnfinal_kernel(const float* __restrict__ sums, const float* __restrict__ gamma,
                               const float* __restrict__ beta, float* __restrict__ scale,
                               float* __restrict__ shift, int N, float invM) {
    int c = blockIdx.x * blockDim.x + threadIdx.x;
    if (c < N) {
        float mean = sums[c] * invM;
        float var = sums[N + c] * invM - mean * mean;
        float sc = gamma[c] * rsqrtf(var + BN_EPS);
        scale[c] = sc;
        shift[c] = beta[c] - mean * sc;
    }
}

// ---------------- tiled fp32 GEMM: C = op(A) @ W + bias ----------------
template <bool BNRELU_A, bool RELU_OUT>
__global__ __launch_bounds__(256) void gemm_kernel(const float* __restrict__ A,
                                                   const float* __restrict__ W,
                                                   const float* __restrict__ bias,
                                                   const float* __restrict__ scale,
                                                   const float* __restrict__ shift,
                                                   float* __restrict__ C, int M, int K, int N) {
    __shared__ __align__(16) float As[16][68];
    __shared__ __align__(16) float Bs[16][64];
    const int tid = threadIdx.x;
    const int tx = tid & 15;
    const int ty = tid >> 4;
    const int m0 = blockIdx.x * 64;
    const int n0 = blockIdx.y * 64;

    float c[4][4] = {};

    for (int k0 = 0; k0 < K; k0 += 16) {
#pragma unroll
        for (int i = 0; i < 4; ++i) {
            int lin = tid + i * 256;
            int m = lin >> 4;
            int k = lin & 15;
            int gm = m0 + m;
            int gk = k0 + k;
            float v = 0.f;
            if (gm < M && gk < K) {
                v = A[(size_t)gm * K + gk];
                if (BNRELU_A) v = fmaxf(v * scale[gk] + shift[gk], 0.f);
            }
            As[k][m] = v;
        }
#pragma unroll
        for (int i = 0; i < 4; ++i) {
            int lin = tid + i * 256;
            int k = lin >> 6;
            int n = lin & 63;
            int gk = k0 + k;
            float v = 0.f;
            if (gk < K) v = W[(size_t)gk * N + n0 + n];
            Bs[k][n] = v;
        }
        __syncthreads();
#pragma unroll
        for (int kk = 0; kk < 16; ++kk) {
            float4 a = *(const float4*)&As[kk][ty * 4];
            float4 b = *(const float4*)&Bs[kk][tx * 4];
            c[0][0] += a.x * b.x; c[0][1] += a.x * b.y; c[0][2] += a.x * b.z; c[0][3] += a.x * b.w;
            c[1][0] += a.y * b.x; c[1][1] += a.y * b.y; c[1][2] += a.y * b.z; c[1][3] += a.y * b.w;
            c[2][0] += a.z * b.x; c[2][1] += a.z * b.y; c[2][2] += a.z * b.z; c[2][3] += a.z * b.w;
            c[3][0] += a.w * b.x; c[3][1] += a.w * b.y; c[3][2] += a.w * b.z; c[3][3] += a.w * b.w;
        }
        __syncthreads();
    }

#pragma unroll
    for (int i = 0; i < 4; ++i) {
        int gm = m0 + ty * 4 + i;
        if (gm >= M) continue;
#pragma unroll
        for (int j = 0; j < 4; ++j) {
            int gn = n0 + tx * 4 + j;
            float v = c[i][j] + bias[gn];
            if (RELU_OUT) v = fmaxf(v, 0.f);
            C[(size_t)gm * N + gn] = v;
        }
    }
}

// ---------------- global add pool: g[batch[n]] += h[n] ----------------
__global__ __launch_bounds__(256) void pool_kernel(const float* __restrict__ h,
                                                   const int* __restrict__ batch,
                                                   float* __restrict__ g) {
    int gid = blockIdx.x * 256 + threadIdx.x;
    if (gid >= NNODES * 32) return;
    int node = gid >> 5;
    int c4 = gid & 31;
    int b = batch[node];
    float4 v = *(const float4*)&h[(size_t)node * 128 + c4 * 4];
    float* gp = &g[(size_t)b * 128 + c4 * 4];
    atomicAdd(gp + 0, v.x);
    atomicAdd(gp + 1, v.y);
    atomicAdd(gp + 2, v.z);
    atomicAdd(gp + 3, v.w);
}

extern "C" void kernel_launch(void* const* d_in, const int* in_sizes, int n_in, void* d_out,
                              int out_size, void* d_ws, size_t ws_size, hipStream_t stream) {
    const float* x = (const float*)d_in[0];
    const int* ei = (const int*)d_in[1];
    const int* batch = (const int*)d_in[2];
    const int* srcA = ei;
    const int* dstA = ei + NEDGES;

    const float* gw1[3] = {(const float*)d_in[3], (const float*)d_in[9], (const float*)d_in[15]};
    const float* gb1[3] = {(const float*)d_in[4], (const float*)d_in[10], (const float*)d_in[16]};
    const float* gga[3] = {(const float*)d_in[5], (const float*)d_in[11], (const float*)d_in[17]};
    const float* gbe[3] = {(const float*)d_in[6], (const float*)d_in[12], (const float*)d_in[18]};
    const float* gw2[3] = {(const float*)d_in[7], (const float*)d_in[13], (const float*)d_in[19]};
    const float* gb2[3] = {(const float*)d_in[8], (const float*)d_in[14], (const float*)d_in[20]};
    const float* fc0_w = (const float*)d_in[21];
    const float* fc0_b = (const float*)d_in[22];
    const float* fc1_w = (const float*)d_in[23];
    const float* fc1_b = (const float*)d_in[24];

    // --- workspace layout ---
    // Two N x 256 fp32 regions (rotation), small stats, pooled, fc hidden, CSR arrays.
    float* ws = (float*)d_ws;
    const size_t BUF = (size_t)NNODES * 256;
    float* R0 = ws;
    float* R1 = R0 + BUF;
    float* stats = R1 + BUF;                // 2*256
    float* scsh = stats + 512;              // 2*256 (scale, shift)
    float* g = scsh + 512;                  // 2048*128 pooled
    float* gh = g + (size_t)NGRAPHS * 128;  // 2048*1024 fc hidden
    int* deg = (int*)(gh + (size_t)NGRAPHS * 1024);  // NNODES
    int* rowptr = deg + NNODES;                      // NNODES+1
    int* cursor = rowptr + NNODES + 4;               // NNODES (keep 16B align)
    int* adj = cursor + NNODES;                      // NEDGES
    // total ~223 MB

    // --- build CSR once (reused by all 3 layers) ---
    hipMemsetAsync(deg, 0, NNODES * sizeof(int), stream);
    deg_kernel<<<(NEDGES + 255) / 256, 256, 0, stream>>>(dstA, deg);
    scan_kernel<<<1, 1024, 0, stream>>>(deg, rowptr, cursor);
    fill_kernel<<<(NEDGES + 255) / 256, 256, 0, stream>>>(srcA, dstA, cursor, adj);

    float* aggP[3] = {R0, R1, R0};
    float* h1P[3] = {R1, R0, R1};
    float* outP[3] = {R0, R1, R0};

    const int dims_out[3] = {128, 256, 128};
    const int dims_in[3] = {66, 128, 256};

    const float* xin = x;
    for (int L = 0; L < 3; ++L) {
        int din = dims_in[L];
        int dout = dims_out[L];
        float* agg = aggP[L];
        float* h1 = h1P[L];
        float* out = outP[L];
        // agg = xin + gather(xin)
        if (din == 66)
            gather_kernel<66, 2><<<(NNODES * 33 + 255) / 256, 256, 0, stream>>>(xin, rowptr, adj, agg);
        else if (din == 128)
            gather_kernel<128, 4><<<(NNODES * 32 + 255) / 256, 256, 0, stream>>>(xin, rowptr, adj, agg);
        else
            gather_kernel<256, 4><<<(NNODES * 64 + 255) / 256, 256, 0, stream>>>(xin, rowptr, adj, agg);
        // h1 = agg @ w1 + b1
        dim3 grid1((NNODES + 63) / 64, dout / 64);
        gemm_kernel<false, false><<<grid1, 256, 0, stream>>>(agg, gw1[L], gb1[L], nullptr, nullptr,
                                                             h1, NNODES, din, dout);
        // BN stats -> scale/shift
        hipMemsetAsync(stats, 0, 2 * dout * sizeof(float), stream);
        if (dout == 128)
            bnstats_kernel<128><<<128, 256, 0, stream>>>(h1, stats);
        else
            bnstats_kernel<256><<<256, 256, 0, stream>>>(h1, stats);
        bnfinal_kernel<<<1, dout, 0, stream>>>(stats, gga[L], gbe[L], scsh, scsh + dout, dout,
                                               1.0f / NNODES);
        // out = relu( relu(bn(h1)) @ w2 + b2 )
        dim3 grid2((NNODES + 63) / 64, dout / 64);
        gemm_kernel<true, true><<<grid2, 256, 0, stream>>>(h1, gw2[L], gb2[L], scsh, scsh + dout,
                                                           out, NNODES, dout, dout);
        xin = out;
    }

    // global add pool (output dim 128)
    hipMemsetAsync(g, 0, (size_t)NGRAPHS * 128 * sizeof(float), stream);
    pool_kernel<<<(NNODES * 32 + 255) / 256, 256, 0, stream>>>(outP[2], batch, g);

    // fc0: relu(g @ fc0_w + fc0_b)
    gemm_kernel<false, true><<<dim3(NGRAPHS / 64, 1024 / 64), 256, 0, stream>>>(
        g, fc0_w, fc0_b, nullptr, nullptr, gh, NGRAPHS, 128, 1024);
    // fc1: gh @ fc1_w + fc1_b -> d_out
    gemm_kernel<false, false><<<dim3(NGRAPHS / 64, 128 / 64), 256, 0, stream>>>(
        gh, fc1_w, fc1_b, nullptr, nullptr, (float*)d_out, NGRAPHS, 1024, 128);
}

// Round 4
// 2309.626 us; speedup vs baseline: 4.5358x; 1.0523x over previous
//
#include <hip/hip_runtime.h>

#define NNODES 100000
#define NEDGES 1600000
#define NGRAPHS 2048
#define BN_EPS 1e-5f

// ---------------- CSR build ----------------
__global__ __launch_bounds__(256) void deg_kernel(const int* __restrict__ dstA,
                                                  int* __restrict__ deg) {
    int e = blockIdx.x * 256 + threadIdx.x;
    if (e < NEDGES) atomicAdd(&deg[dstA[e]], 1);
}

// single-block exclusive scan over deg[0..NNODES) -> rowptr[0..NNODES], cursor copy
__global__ __launch_bounds__(1024) void scan_kernel(const int* __restrict__ deg,
                                                    int* __restrict__ rowptr,
                                                    int* __restrict__ cursor) {
    __shared__ int part[1024];
    const int t = threadIdx.x;
    const int CH = (NNODES + 1023) / 1024;
    int lo = t * CH;
    int hi = lo + CH;
    if (hi > NNODES) hi = NNODES;
    int s = 0;
    for (int i = lo; i < hi; ++i) s += deg[i];
    part[t] = s;
    __syncthreads();
    for (int off = 1; off < 1024; off <<= 1) {
        int v = (t >= off) ? part[t - off] : 0;
        __syncthreads();
        part[t] += v;
        __syncthreads();
    }
    int run = (t == 0) ? 0 : part[t - 1];
    for (int i = lo; i < hi; ++i) {
        rowptr[i] = run;
        cursor[i] = run;
        run += deg[i];
    }
    if (t == 1023) rowptr[NNODES] = part[1023];
}

__global__ __launch_bounds__(256) void fill_kernel(const int* __restrict__ srcA,
                                                   const int* __restrict__ dstA,
                                                   int* __restrict__ cursor,
                                                   int* __restrict__ adj) {
    int e = blockIdx.x * 256 + threadIdx.x;
    if (e < NEDGES) {
        int d = dstA[e];
        int loc = atomicAdd(&cursor[d], 1);
        adj[loc] = srcA[e];
    }
}

// ---------------- gather aggregation: agg[n] = x[n] + sum_{s in adj[n]} x[s] (+bias) ----------
template <int DIM, int CHUNK>
__global__ __launch_bounds__(256) void gather_kernel(const float* __restrict__ x,
                                                     const int* __restrict__ rowptr,
                                                     const int* __restrict__ adj,
                                                     float* __restrict__ agg,
                                                     const float* __restrict__ bias) {
    constexpr int PE = DIM / CHUNK;
    int gid = blockIdx.x * 256 + threadIdx.x;
    if (gid >= NNODES * PE) return;
    int node = gid / PE;
    int c = gid - node * PE;
    const int beg = rowptr[node];
    const int end = rowptr[node + 1];
    if (CHUNK == 4) {
        const float4* xp = (const float4*)x;
        float4 acc = xp[(size_t)node * PE + c];
        for (int i = beg; i < end; ++i) {
            int s = adj[i];
            float4 v = xp[(size_t)s * PE + c];
            acc.x += v.x;
            acc.y += v.y;
            acc.z += v.z;
            acc.w += v.w;
        }
        if (bias) {
            float4 b = *(const float4*)&bias[c * 4];
            acc.x += b.x; acc.y += b.y; acc.z += b.z; acc.w += b.w;
        }
        ((float4*)agg)[(size_t)node * PE + c] = acc;
    } else {
        const float2* xp = (const float2*)x;
        float2 acc = xp[(size_t)node * PE + c];
        for (int i = beg; i < end; ++i) {
            int s = adj[i];
            float2 v = xp[(size_t)s * PE + c];
            acc.x += v.x;
            acc.y += v.y;
        }
        ((float2*)agg)[(size_t)node * PE + c] = acc;
    }
}

// ---------------- BN stats (standalone, used once for L2) ----------------
template <int N>
__global__ __launch_bounds__(256) void bnstats_kernel(const float* __restrict__ h,
                                                      float* __restrict__ sums) {
    constexpr int SHIFT = (N == 128) ? 7 : 8;
    int t = blockIdx.x * 256 + threadIdx.x;
    int col = t & (N - 1);
    int slice = t >> SHIFT;
    float s = 0.f, s2 = 0.f;
    for (int r = slice; r < NNODES; r += 256) {
        float v = h[(size_t)r * N + col];
        s += v;
        s2 += v * v;
    }
    atomicAdd(&sums[col], s);
    atomicAdd(&sums[N + col], s2);
}

__global__ void bnfinal_kernel(const float* __restrict__ sums, const float* __restrict__ gamma,
                               const float* __restrict__ beta, float* __restrict__ scale,
                               float* __restrict__ shift, int N, float invM) {
    int c = blockIdx.x * blockDim.x + threadIdx.x;
    if (c < N) {
        float mean = sums[c] * invM;
        float var = sums[N + c] * invM - mean * mean;
        float sc = gamma[c] * rsqrtf(var + BN_EPS);
        scale[c] = sc;
        shift[c] = beta[c] - mean * sc;
    }
}

__device__ __forceinline__ void fma44(float (&cc)[4][4], const float4& a, const float4& b) {
    cc[0][0] += a.x * b.x; cc[0][1] += a.x * b.y; cc[0][2] += a.x * b.z; cc[0][3] += a.x * b.w;
    cc[1][0] += a.y * b.x; cc[1][1] += a.y * b.y; cc[1][2] += a.y * b.z; cc[1][3] += a.y * b.w;
    cc[2][0] += a.z * b.x; cc[2][1] += a.z * b.y; cc[2][2] += a.z * b.z; cc[2][3] += a.z * b.w;
    cc[3][0] += a.w * b.x; cc[3][1] += a.w * b.y; cc[3][2] += a.w * b.z; cc[3][3] += a.w * b.w;
}

// ---------------- 128x128 tile fp32 GEMM, 8x8/thread (2x2 quadrants of 4x4) ---------------
// A: MxK row-major, W: KxN row-major. 256 threads. BK=16.
// BNRELU_A: A elem -> relu(A*scale[k]+shift[k]). RELU_OUT: relu epilogue.
// FUSE_STATS: per-column sum/sumsq of (C+bias) atomically added into stats[0..N),[N..2N).
// bias may be nullptr.
template <bool BNRELU_A, bool RELU_OUT, bool FUSE_STATS>
__global__ __launch_bounds__(256) void gemm128_kernel(
    const float* __restrict__ A, const float* __restrict__ W, const float* __restrict__ bias,
    const float* __restrict__ scale, const float* __restrict__ shift, float* __restrict__ C,
    float* __restrict__ stats, int M, int K, int N) {
    __shared__ __align__(16) float As[16][132];  // [k][m] transposed; 132 stride (16B-aligned rows)
    __shared__ __align__(16) float Bs[16][128];  // [k][n]
    __shared__ float sstat[256];                 // 128 sum + 128 sumsq
    const int tid = threadIdx.x;
    const int tx = tid & 15;
    const int ty = tid >> 4;
    const int m0 = blockIdx.x * 128;
    const int n0 = blockIdx.y * 128;

    if (FUSE_STATS) sstat[tid] = 0.f;  // synced by first k-loop barrier

    float c[2][2][4][4] = {};
    const bool k4 = ((K & 3) == 0);

    for (int k0 = 0; k0 < K; k0 += 16) {
        // ---- stage A tile (128 rows x 16 k) transposed into As[k][m] ----
        if (k4) {
#pragma unroll
            for (int i = 0; i < 2; ++i) {
                int lin4 = tid + i * 256;  // [0,512)
                int row = lin4 >> 2;       // 0..127
                int kq = lin4 & 3;         // 0..3 (k-quad)
                int gm = m0 + row;
                float4 v = make_float4(0.f, 0.f, 0.f, 0.f);
                if (gm < M) v = *(const float4*)&A[(size_t)gm * K + k0 + kq * 4];
                if (BNRELU_A) {
                    int gk = k0 + kq * 4;
                    v.x = fmaxf(v.x * scale[gk + 0] + shift[gk + 0], 0.f);
                    v.y = fmaxf(v.y * scale[gk + 1] + shift[gk + 1], 0.f);
                    v.z = fmaxf(v.z * scale[gk + 2] + shift[gk + 2], 0.f);
                    v.w = fmaxf(v.w * scale[gk + 3] + shift[gk + 3], 0.f);
                }
                As[kq * 4 + 0][row] = v.x;
                As[kq * 4 + 1][row] = v.y;
                As[kq * 4 + 2][row] = v.z;
                As[kq * 4 + 3][row] = v.w;
            }
        } else {  // K not multiple of 4 (K=66): scalar guarded path
#pragma unroll
            for (int i = 0; i < 8; ++i) {
                int lin = tid + i * 256;  // [0,2048)
                int row = lin >> 4;
                int k = lin & 15;
                int gm = m0 + row;
                int gk = k0 + k;
                float v = 0.f;
                if (gm < M && gk < K) {
                    v = A[(size_t)gm * K + gk];
                    if (BNRELU_A) v = fmaxf(v * scale[gk] + shift[gk], 0.f);
                }
                As[k][row] = v;
            }
        }
        // ---- stage W tile (16 k x 128 n) ----
#pragma unroll
        for (int i = 0; i < 2; ++i) {
            int lin4 = tid + i * 256;  // [0,512)
            int kr = lin4 >> 5;        // 0..15
            int nq = lin4 & 31;        // 0..31
            int gk = k0 + kr;
            float4 v = make_float4(0.f, 0.f, 0.f, 0.f);
            if (gk < K) v = *(const float4*)&W[(size_t)gk * N + n0 + nq * 4];
            *(float4*)&Bs[kr][nq * 4] = v;
        }
        __syncthreads();
#pragma unroll
        for (int kk = 0; kk < 16; ++kk) {
            float4 a0 = *(const float4*)&As[kk][ty * 4];
            float4 a1 = *(const float4*)&As[kk][64 + ty * 4];
            float4 b0 = *(const float4*)&Bs[kk][tx * 4];
            float4 b1 = *(const float4*)&Bs[kk][64 + tx * 4];
            fma44(c[0][0], a0, b0);
            fma44(c[0][1], a0, b1);
            fma44(c[1][0], a1, b0);
            fma44(c[1][1], a1, b1);
        }
        __syncthreads();
    }

    // ---- epilogue: bias (+relu) store, optional fused column stats ----
    float s_sum[8] = {}, s_sq[8] = {};
    const bool hasb = (bias != nullptr);
#pragma unroll
    for (int qa = 0; qa < 2; ++qa) {
#pragma unroll
        for (int i = 0; i < 4; ++i) {
            int gm = m0 + qa * 64 + ty * 4 + i;
            if (gm >= M) continue;
#pragma unroll
            for (int qb = 0; qb < 2; ++qb) {
                int gn = n0 + qb * 64 + tx * 4;
                float4 v;
                v.x = c[qa][qb][i][0] + (hasb ? bias[gn + 0] : 0.f);
                v.y = c[qa][qb][i][1] + (hasb ? bias[gn + 1] : 0.f);
                v.z = c[qa][qb][i][2] + (hasb ? bias[gn + 2] : 0.f);
                v.w = c[qa][qb][i][3] + (hasb ? bias[gn + 3] : 0.f);
                if (RELU_OUT) {
                    v.x = fmaxf(v.x, 0.f); v.y = fmaxf(v.y, 0.f);
                    v.z = fmaxf(v.z, 0.f); v.w = fmaxf(v.w, 0.f);
                }
                *(float4*)&C[(size_t)gm * N + gn] = v;
                if (FUSE_STATS) {
                    s_sum[qb * 4 + 0] += v.x; s_sq[qb * 4 + 0] += v.x * v.x;
                    s_sum[qb * 4 + 1] += v.y; s_sq[qb * 4 + 1] += v.y * v.y;
                    s_sum[qb * 4 + 2] += v.z; s_sq[qb * 4 + 2] += v.z * v.z;
                    s_sum[qb * 4 + 3] += v.w; s_sq[qb * 4 + 3] += v.w * v.w;
                }
            }
        }
    }
    if (FUSE_STATS) {
#pragma unroll
        for (int qb = 0; qb < 2; ++qb)
#pragma unroll
            for (int j = 0; j < 4; ++j) {
                int cl = qb * 64 + tx * 4 + j;
                atomicAdd(&sstat[cl], s_sum[qb * 4 + j]);
                atomicAdd(&sstat[128 + cl], s_sq[qb * 4 + j]);
            }
        __syncthreads();
        if (tid < 128) {
            atomicAdd(&stats[n0 + tid], sstat[tid]);
            atomicAdd(&stats[N + n0 + tid], sstat[128 + tid]);
        }
    }
}

// ---------------- 64x64 tile fp32 GEMM (kept for fc0/fc1) ----------------
template <bool RELU_OUT>
__global__ __launch_bounds__(256) void gemm64_kernel(const float* __restrict__ A,
                                                     const float* __restrict__ W,
                                                     const float* __restrict__ bias,
                                                     float* __restrict__ C, int M, int K, int N) {
    __shared__ __align__(16) float As[16][68];
    __shared__ __align__(16) float Bs[16][64];
    const int tid = threadIdx.x;
    const int tx = tid & 15;
    const int ty = tid >> 4;
    const int m0 = blockIdx.x * 64;
    const int n0 = blockIdx.y * 64;

    float c[4][4] = {};

    for (int k0 = 0; k0 < K; k0 += 16) {
#pragma unroll
        for (int i = 0; i < 4; ++i) {
            int lin = tid + i * 256;
            int m = lin >> 4;
            int k = lin & 15;
            int gm = m0 + m;
            int gk = k0 + k;
            float v = 0.f;
            if (gm < M && gk < K) v = A[(size_t)gm * K + gk];
            As[k][m] = v;
        }
#pragma unroll
        for (int i = 0; i < 4; ++i) {
            int lin = tid + i * 256;
            int k = lin >> 6;
            int n = lin & 63;
            int gk = k0 + k;
            float v = 0.f;
            if (gk < K) v = W[(size_t)gk * N + n0 + n];
            Bs[k][n] = v;
        }
        __syncthreads();
#pragma unroll
        for (int kk = 0; kk < 16; ++kk) {
            float4 a = *(const float4*)&As[kk][ty * 4];
            float4 b = *(const float4*)&Bs[kk][tx * 4];
            c[0][0] += a.x * b.x; c[0][1] += a.x * b.y; c[0][2] += a.x * b.z; c[0][3] += a.x * b.w;
            c[1][0] += a.y * b.x; c[1][1] += a.y * b.y; c[1][2] += a.y * b.z; c[1][3] += a.y * b.w;
            c[2][0] += a.z * b.x; c[2][1] += a.z * b.y; c[2][2] += a.z * b.z; c[2][3] += a.z * b.w;
            c[3][0] += a.w * b.x; c[3][1] += a.w * b.y; c[3][2] += a.w * b.z; c[3][3] += a.w * b.w;
        }
        __syncthreads();
    }

#pragma unroll
    for (int i = 0; i < 4; ++i) {
        int gm = m0 + ty * 4 + i;
        if (gm >= M) continue;
#pragma unroll
        for (int j = 0; j < 4; ++j) {
            int gn = n0 + tx * 4 + j;
            float v = c[i][j] + bias[gn];
            if (RELU_OUT) v = fmaxf(v, 0.f);
            C[(size_t)gm * N + gn] = v;
        }
    }
}

// ---------------- global add pool ----------------
__global__ __launch_bounds__(256) void pool_kernel(const float* __restrict__ h,
                                                   const int* __restrict__ batch,
                                                   float* __restrict__ g) {
    int gid = blockIdx.x * 256 + threadIdx.x;
    if (gid >= NNODES * 32) return;
    int node = gid >> 5;
    int c4 = gid & 31;
    int b = batch[node];
    float4 v = *(const float4*)&h[(size_t)node * 128 + c4 * 4];
    float* gp = &g[(size_t)b * 128 + c4 * 4];
    atomicAdd(gp + 0, v.x);
    atomicAdd(gp + 1, v.y);
    atomicAdd(gp + 2, v.z);
    atomicAdd(gp + 3, v.w);
}

extern "C" void kernel_launch(void* const* d_in, const int* in_sizes, int n_in, void* d_out,
                              int out_size, void* d_ws, size_t ws_size, hipStream_t stream) {
    const float* x = (const float*)d_in[0];
    const int* ei = (const int*)d_in[1];
    const int* batch = (const int*)d_in[2];
    const int* srcA = ei;
    const int* dstA = ei + NEDGES;

    const float* g0_w1 = (const float*)d_in[3];
    const float* g0_b1 = (const float*)d_in[4];
    const float* g0_ga = (const float*)d_in[5];
    const float* g0_be = (const float*)d_in[6];
    const float* g0_w2 = (const float*)d_in[7];
    const float* g0_b2 = (const float*)d_in[8];
    const float* g1_w1 = (const float*)d_in[9];
    const float* g1_b1 = (const float*)d_in[10];
    const float* g1_ga = (const float*)d_in[11];
    const float* g1_be = (const float*)d_in[12];
    const float* g1_w2 = (const float*)d_in[13];
    const float* g1_b2 = (const float*)d_in[14];
    const float* g2_w1 = (const float*)d_in[15];
    const float* g2_b1 = (const float*)d_in[16];
    const float* g2_ga = (const float*)d_in[17];
    const float* g2_be = (const float*)d_in[18];
    const float* g2_w2 = (const float*)d_in[19];
    const float* g2_b2 = (const float*)d_in[20];
    const float* fc0_w = (const float*)d_in[21];
    const float* fc0_b = (const float*)d_in[22];
    const float* fc1_w = (const float*)d_in[23];
    const float* fc1_b = (const float*)d_in[24];

    // --- workspace layout (~222 MB) ---
    float* ws = (float*)d_ws;
    const size_t BUF = (size_t)NNODES * 256;
    float* R0 = ws;
    float* R1 = R0 + BUF;
    float* stats = R1 + BUF;                         // 2*256
    float* scsh = stats + 512;                       // 2*256 (scale, shift)
    float* g = scsh + 512;                           // 2048*128 pooled
    float* gh = g + (size_t)NGRAPHS * 128;           // 2048*1024 fc hidden
    int* deg = (int*)(gh + (size_t)NGRAPHS * 1024);  // NNODES
    int* rowptr = deg + NNODES;                      // NNODES+1
    int* cursor = rowptr + NNODES + 4;               // NNODES
    int* adj = cursor + NNODES;                      // NEDGES

    const int MB = (NNODES + 127) / 128;  // 782 row-blocks

    // --- build CSR once ---
    hipMemsetAsync(deg, 0, NNODES * sizeof(int), stream);
    deg_kernel<<<(NEDGES + 255) / 256, 256, 0, stream>>>(dstA, deg);
    scan_kernel<<<1, 1024, 0, stream>>>(deg, rowptr, cursor);
    fill_kernel<<<(NEDGES + 255) / 256, 256, 0, stream>>>(srcA, dstA, cursor, adj);

    // ================= Layer 0 (66 -> 128 -> 128) =================
    // gather at 66, GEMM1 fused stats, GEMM2
    gather_kernel<66, 2><<<(NNODES * 33 + 255) / 256, 256, 0, stream>>>(x, rowptr, adj, R0, nullptr);
    hipMemsetAsync(stats, 0, 2 * 128 * sizeof(float), stream);
    gemm128_kernel<false, false, true><<<dim3(MB, 1), 256, 0, stream>>>(
        R0, g0_w1, g0_b1, nullptr, nullptr, R1, stats, NNODES, 66, 128);
    bnfinal_kernel<<<1, 128, 0, stream>>>(stats, g0_ga, g0_be, scsh, scsh + 128, 128, 1.0f / NNODES);
    gemm128_kernel<true, true, false><<<dim3(MB, 1), 256, 0, stream>>>(
        R1, g0_w2, g0_b2, scsh, scsh + 128, R0, nullptr, NNODES, 128, 128);

    // ================= Layer 1 (128 -> 256 -> 256) =================
    gather_kernel<128, 4><<<(NNODES * 32 + 255) / 256, 256, 0, stream>>>(R0, rowptr, adj, R1, nullptr);
    hipMemsetAsync(stats, 0, 2 * 256 * sizeof(float), stream);
    gemm128_kernel<false, false, true><<<dim3(MB, 2), 256, 0, stream>>>(
        R1, g1_w1, g1_b1, nullptr, nullptr, R0, stats, NNODES, 128, 256);
    bnfinal_kernel<<<1, 256, 0, stream>>>(stats, g1_ga, g1_be, scsh, scsh + 256, 256, 1.0f / NNODES);
    gemm128_kernel<true, true, false><<<dim3(MB, 2), 256, 0, stream>>>(
        R0, g1_w2, g1_b2, scsh, scsh + 256, R1, nullptr, NNODES, 256, 256);

    // ================= Layer 2 (256 -> 128 -> 128), REORDERED =================
    // GINConv is linear in x: (x + sum_j x_j) @ W1 + b1 == (x@W1) + sum_j (x@W1)_j + b1.
    // GEMM1 first (no bias, no stats), gather at dim 128 (adds b1), then bnstats.
    gemm128_kernel<false, false, false><<<dim3(MB, 1), 256, 0, stream>>>(
        R1, g2_w1, nullptr, nullptr, nullptr, R0, nullptr, NNODES, 256, 128);
    gather_kernel<128, 4><<<(NNODES * 32 + 255) / 256, 256, 0, stream>>>(R0, rowptr, adj, R1, g2_b1);
    hipMemsetAsync(stats, 0, 2 * 128 * sizeof(float), stream);
    bnstats_kernel<128><<<128, 256, 0, stream>>>(R1, stats);
    bnfinal_kernel<<<1, 128, 0, stream>>>(stats, g2_ga, g2_be, scsh, scsh + 128, 128, 1.0f / NNODES);
    gemm128_kernel<true, true, false><<<dim3(MB, 1), 256, 0, stream>>>(
        R1, g2_w2, g2_b2, scsh, scsh + 128, R0, nullptr, NNODES, 128, 128);

    // ================= pool + FC head =================
    hipMemsetAsync(g, 0, (size_t)NGRAPHS * 128 * sizeof(float), stream);
    pool_kernel<<<(NNODES * 32 + 255) / 256, 256, 0, stream>>>(R0, batch, g);

    gemm64_kernel<true><<<dim3(NGRAPHS / 64, 1024 / 64), 256, 0, stream>>>(g, fc0_w, fc0_b, gh,
                                                                           NGRAPHS, 128, 1024);
    gemm64_kernel<false><<<dim3(NGRAPHS / 64, 128 / 64), 256, 0, stream>>>(
        gh, fc1_w, fc1_b, (float*)d_out, NGRAPHS, 1024, 128);
}

// Round 5
// 1960.950 us; speedup vs baseline: 5.3423x; 1.1778x over previous
//
#include <hip/hip_runtime.h>

#define NNODES 100000
#define NEDGES 1600000
#define NGRAPHS 2048
#define BN_EPS 1e-5f

// ---------------- CSR build ----------------
__global__ __launch_bounds__(256) void deg_kernel(const int* __restrict__ dstA,
                                                  int* __restrict__ deg) {
    int e = blockIdx.x * 256 + threadIdx.x;
    if (e < NEDGES) atomicAdd(&deg[dstA[e]], 1);
}

// single-block exclusive scan over deg[0..NNODES) -> rowptr[0..NNODES], cursor copy
__global__ __launch_bounds__(1024) void scan_kernel(const int* __restrict__ deg,
                                                    int* __restrict__ rowptr,
                                                    int* __restrict__ cursor) {
    __shared__ int part[1024];
    const int t = threadIdx.x;
    const int CH = (NNODES + 1023) / 1024;
    int lo = t * CH;
    int hi = lo + CH;
    if (hi > NNODES) hi = NNODES;
    int s = 0;
    for (int i = lo; i < hi; ++i) s += deg[i];
    part[t] = s;
    __syncthreads();
    for (int off = 1; off < 1024; off <<= 1) {
        int v = (t >= off) ? part[t - off] : 0;
        __syncthreads();
        part[t] += v;
        __syncthreads();
    }
    int run = (t == 0) ? 0 : part[t - 1];
    for (int i = lo; i < hi; ++i) {
        rowptr[i] = run;
        cursor[i] = run;
        run += deg[i];
    }
    if (t == 1023) rowptr[NNODES] = part[1023];
}

__global__ __launch_bounds__(256) void fill_kernel(const int* __restrict__ srcA,
                                                   const int* __restrict__ dstA,
                                                   int* __restrict__ cursor,
                                                   int* __restrict__ adj) {
    int e = blockIdx.x * 256 + threadIdx.x;
    if (e < NEDGES) {
        int d = dstA[e];
        int loc = atomicAdd(&cursor[d], 1);
        adj[loc] = srcA[e];
    }
}

// ------- gather aggregation: agg[n] = x[n] + sum_{s in adj[n]} x[s] (+bias) -------
// DIM: input row width (floats). OSTRIDE: output row stride (floats) — may pad.
template <int DIM, int CHUNK, int OSTRIDE>
__global__ __launch_bounds__(256) void gather_kernel(const float* __restrict__ x,
                                                     const int* __restrict__ rowptr,
                                                     const int* __restrict__ adj,
                                                     float* __restrict__ agg,
                                                     const float* __restrict__ bias) {
    constexpr int PE = DIM / CHUNK;
    int gid = blockIdx.x * 256 + threadIdx.x;
    if (gid >= NNODES * PE) return;
    int node = gid / PE;
    int c = gid - node * PE;
    const int beg = rowptr[node];
    const int end = rowptr[node + 1];
    if (CHUNK == 4) {
        const float4* xp = (const float4*)x;
        float4 acc = xp[(size_t)node * PE + c];
        for (int i = beg; i < end; ++i) {
            int s = adj[i];
            float4 v = xp[(size_t)s * PE + c];
            acc.x += v.x;
            acc.y += v.y;
            acc.z += v.z;
            acc.w += v.w;
        }
        if (bias) {
            float4 b = *(const float4*)&bias[c * 4];
            acc.x += b.x; acc.y += b.y; acc.z += b.z; acc.w += b.w;
        }
        *(float4*)&agg[(size_t)node * OSTRIDE + c * 4] = acc;
    } else {
        const float2* xp = (const float2*)x;
        float2 acc = xp[(size_t)node * PE + c];
        for (int i = beg; i < end; ++i) {
            int s = adj[i];
            float2 v = xp[(size_t)s * PE + c];
            acc.x += v.x;
            acc.y += v.y;
        }
        *(float2*)&agg[(size_t)node * OSTRIDE + c * 2] = acc;
    }
}

// ---------------- BN stats (standalone, used once for L2) ----------------
template <int N>
__global__ __launch_bounds__(256) void bnstats_kernel(const float* __restrict__ h,
                                                      float* __restrict__ sums) {
    constexpr int SHIFT = (N == 128) ? 7 : 8;
    int t = blockIdx.x * 256 + threadIdx.x;
    int col = t & (N - 1);
    int slice = t >> SHIFT;
    float s = 0.f, s2 = 0.f;
    for (int r = slice; r < NNODES; r += 256) {
        float v = h[(size_t)r * N + col];
        s += v;
        s2 += v * v;
    }
    atomicAdd(&sums[col], s);
    atomicAdd(&sums[N + col], s2);
}

__global__ void bnfinal_kernel(const float* __restrict__ sums, const float* __restrict__ gamma,
                               const float* __restrict__ beta, float* __restrict__ scale,
                               float* __restrict__ shift, int N, float invM) {
    int c = blockIdx.x * blockDim.x + threadIdx.x;
    if (c < N) {
        float mean = sums[c] * invM;
        float var = sums[N + c] * invM - mean * mean;
        float sc = gamma[c] * rsqrtf(var + BN_EPS);
        scale[c] = sc;
        shift[c] = beta[c] - mean * sc;
    }
}

__device__ __forceinline__ void fma44(float (&cc)[4][4], const float4& a, const float4& b) {
    cc[0][0] += a.x * b.x; cc[0][1] += a.x * b.y; cc[0][2] += a.x * b.z; cc[0][3] += a.x * b.w;
    cc[1][0] += a.y * b.x; cc[1][1] += a.y * b.y; cc[1][2] += a.y * b.z; cc[1][3] += a.y * b.w;
    cc[2][0] += a.z * b.x; cc[2][1] += a.z * b.y; cc[2][2] += a.z * b.z; cc[2][3] += a.z * b.w;
    cc[3][0] += a.w * b.x; cc[3][1] += a.w * b.y; cc[3][2] += a.w * b.z; cc[3][3] += a.w * b.w;
}

// ---------------- 128x64 tile fp32 GEMM, 8x4/thread (2 row-quadrants of 4x4) ----------
// A: M x K row-major (K = padded stride & loop bound, 16B-aligned rows => K%4==0).
// W: Kw x N row-major (Kw = real K; rows >= Kw read as 0).
// BNRELU_A: A elem -> relu(A*scale[k]+shift[k]).  RELU_OUT: relu epilogue.
// FUSE_STATS: per-column sum/sumsq of stored C atomically added into stats[0..N),[N..2N).
// VGPR budget ~75 -> 6 waves/SIMD (vs 132/3-waves for the 8x8 variant that starved).
template <bool BNRELU_A, bool RELU_OUT, bool FUSE_STATS>
__global__ __launch_bounds__(256) void gemm128x64_kernel(
    const float* __restrict__ A, const float* __restrict__ W, const float* __restrict__ bias,
    const float* __restrict__ scale, const float* __restrict__ shift, float* __restrict__ C,
    float* __restrict__ stats, int M, int K, int Kw, int N) {
    __shared__ __align__(16) float As[16][132];  // [k][m], 132 stride (16B-aligned rows)
    __shared__ __align__(16) float Bs[16][64];   // [k][n]
    __shared__ float sstat[128];                 // 64 sum + 64 sumsq
    const int tid = threadIdx.x;
    const int tx = tid & 15;   // n quad: tx*4
    const int ty = tid >> 4;   // m quad: ty*4 (+64)
    const int m0 = blockIdx.x * 128;
    const int n0 = blockIdx.y * 64;

    if (FUSE_STATS && tid < 128) sstat[tid] = 0.f;  // synced by first k-loop barrier

    float c[2][4][4] = {};

    for (int k0 = 0; k0 < K; k0 += 16) {
        // ---- stage A tile (128 rows x 16 k) transposed into As[k][m] ----
#pragma unroll
        for (int i = 0; i < 2; ++i) {
            int lin4 = tid + i * 256;  // [0,512)
            int row = lin4 >> 2;       // 0..127
            int kq = lin4 & 3;         // k-quad
            int gm = m0 + row;
            float4 v = make_float4(0.f, 0.f, 0.f, 0.f);
            if (gm < M) v = *(const float4*)&A[(size_t)gm * K + k0 + kq * 4];
            if (BNRELU_A) {
                int gk = k0 + kq * 4;
                v.x = fmaxf(v.x * scale[gk + 0] + shift[gk + 0], 0.f);
                v.y = fmaxf(v.y * scale[gk + 1] + shift[gk + 1], 0.f);
                v.z = fmaxf(v.z * scale[gk + 2] + shift[gk + 2], 0.f);
                v.w = fmaxf(v.w * scale[gk + 3] + shift[gk + 3], 0.f);
            }
            As[kq * 4 + 0][row] = v.x;
            As[kq * 4 + 1][row] = v.y;
            As[kq * 4 + 2][row] = v.z;
            As[kq * 4 + 3][row] = v.w;
        }
        // ---- stage W tile (16 k x 64 n): 1 float4 per thread; guard by Kw ----
        {
            int kr = tid >> 4;  // 0..15
            int nq = tid & 15;  // 0..15
            int gk = k0 + kr;
            float4 v = make_float4(0.f, 0.f, 0.f, 0.f);
            if (gk < Kw) v = *(const float4*)&W[(size_t)gk * N + n0 + nq * 4];
            *(float4*)&Bs[kr][nq * 4] = v;
        }
        __syncthreads();
        // ---- inner product with explicit next-kk prefetch ----
        float4 a0 = *(const float4*)&As[0][ty * 4];
        float4 a1 = *(const float4*)&As[0][64 + ty * 4];
        float4 b = *(const float4*)&Bs[0][tx * 4];
#pragma unroll
        for (int kk = 0; kk < 16; ++kk) {
            float4 na0, na1, nb;
            if (kk < 15) {
                na0 = *(const float4*)&As[kk + 1][ty * 4];
                na1 = *(const float4*)&As[kk + 1][64 + ty * 4];
                nb = *(const float4*)&Bs[kk + 1][tx * 4];
            }
            fma44(c[0], a0, b);
            fma44(c[1], a1, b);
            if (kk < 15) {
                a0 = na0;
                a1 = na1;
                b = nb;
            }
        }
        __syncthreads();
    }

    // ---- epilogue: bias (+relu) store, optional fused column stats ----
    float s_sum[4] = {}, s_sq[4] = {};
    const bool hasb = (bias != nullptr);
    const int gn = n0 + tx * 4;
    float4 bv = make_float4(0.f, 0.f, 0.f, 0.f);
    if (hasb) bv = *(const float4*)&bias[gn];
#pragma unroll
    for (int qa = 0; qa < 2; ++qa) {
#pragma unroll
        for (int i = 0; i < 4; ++i) {
            int gm = m0 + qa * 64 + ty * 4 + i;
            if (gm >= M) continue;
            float4 v;
            v.x = c[qa][i][0] + bv.x;
            v.y = c[qa][i][1] + bv.y;
            v.z = c[qa][i][2] + bv.z;
            v.w = c[qa][i][3] + bv.w;
            if (RELU_OUT) {
                v.x = fmaxf(v.x, 0.f); v.y = fmaxf(v.y, 0.f);
                v.z = fmaxf(v.z, 0.f); v.w = fmaxf(v.w, 0.f);
            }
            *(float4*)&C[(size_t)gm * N + gn] = v;
            if (FUSE_STATS) {
                s_sum[0] += v.x; s_sq[0] += v.x * v.x;
                s_sum[1] += v.y; s_sq[1] += v.y * v.y;
                s_sum[2] += v.z; s_sq[2] += v.z * v.z;
                s_sum[3] += v.w; s_sq[3] += v.w * v.w;
            }
        }
    }
    if (FUSE_STATS) {
#pragma unroll
        for (int j = 0; j < 4; ++j) {
            int cl = tx * 4 + j;
            atomicAdd(&sstat[cl], s_sum[j]);
            atomicAdd(&sstat[64 + cl], s_sq[j]);
        }
        __syncthreads();
        if (tid < 64) {
            atomicAdd(&stats[n0 + tid], sstat[tid]);
            atomicAdd(&stats[N + n0 + tid], sstat[64 + tid]);
        }
    }
}

// ---------------- 64x64 tile fp32 GEMM (fc0/fc1 head, tiny) ----------------
template <bool RELU_OUT>
__global__ __launch_bounds__(256) void gemm64_kernel(const float* __restrict__ A,
                                                     const float* __restrict__ W,
                                                     const float* __restrict__ bias,
                                                     float* __restrict__ C, int M, int K, int N) {
    __shared__ __align__(16) float As[16][68];
    __shared__ __align__(16) float Bs[16][64];
    const int tid = threadIdx.x;
    const int tx = tid & 15;
    const int ty = tid >> 4;
    const int m0 = blockIdx.x * 64;
    const int n0 = blockIdx.y * 64;

    float c[4][4] = {};

    for (int k0 = 0; k0 < K; k0 += 16) {
#pragma unroll
        for (int i = 0; i < 4; ++i) {
            int lin = tid + i * 256;
            int m = lin >> 4;
            int k = lin & 15;
            int gm = m0 + m;
            int gk = k0 + k;
            float v = 0.f;
            if (gm < M && gk < K) v = A[(size_t)gm * K + gk];
            As[k][m] = v;
        }
#pragma unroll
        for (int i = 0; i < 4; ++i) {
            int lin = tid + i * 256;
            int k = lin >> 6;
            int n = lin & 63;
            int gk = k0 + k;
            float v = 0.f;
            if (gk < K) v = W[(size_t)gk * N + n0 + n];
            Bs[k][n] = v;
        }
        __syncthreads();
#pragma unroll
        for (int kk = 0; kk < 16; ++kk) {
            float4 a = *(const float4*)&As[kk][ty * 4];
            float4 b = *(const float4*)&Bs[kk][tx * 4];
            c[0][0] += a.x * b.x; c[0][1] += a.x * b.y; c[0][2] += a.x * b.z; c[0][3] += a.x * b.w;
            c[1][0] += a.y * b.x; c[1][1] += a.y * b.y; c[1][2] += a.y * b.z; c[1][3] += a.y * b.w;
            c[2][0] += a.z * b.x; c[2][1] += a.z * b.y; c[2][2] += a.z * b.z; c[2][3] += a.z * b.w;
            c[3][0] += a.w * b.x; c[3][1] += a.w * b.y; c[3][2] += a.w * b.z; c[3][3] += a.w * b.w;
        }
        __syncthreads();
    }

#pragma unroll
    for (int i = 0; i < 4; ++i) {
        int gm = m0 + ty * 4 + i;
        if (gm >= M) continue;
#pragma unroll
        for (int j = 0; j < 4; ++j) {
            int gn = n0 + tx * 4 + j;
            float v = c[i][j] + bias[gn];
            if (RELU_OUT) v = fmaxf(v, 0.f);
            C[(size_t)gm * N + gn] = v;
        }
    }
}

// ---------------- global add pool ----------------
__global__ __launch_bounds__(256) void pool_kernel(const float* __restrict__ h,
                                                   const int* __restrict__ batch,
                                                   float* __restrict__ g) {
    int gid = blockIdx.x * 256 + threadIdx.x;
    if (gid >= NNODES * 32) return;
    int node = gid >> 5;
    int c4 = gid & 31;
    int b = batch[node];
    float4 v = *(const float4*)&h[(size_t)node * 128 + c4 * 4];
    float* gp = &g[(size_t)b * 128 + c4 * 4];
    atomicAdd(gp + 0, v.x);
    atomicAdd(gp + 1, v.y);
    atomicAdd(gp + 2, v.z);
    atomicAdd(gp + 3, v.w);
}

extern "C" void kernel_launch(void* const* d_in, const int* in_sizes, int n_in, void* d_out,
                              int out_size, void* d_ws, size_t ws_size, hipStream_t stream) {
    const float* x = (const float*)d_in[0];
    const int* ei = (const int*)d_in[1];
    const int* batch = (const int*)d_in[2];
    const int* srcA = ei;
    const int* dstA = ei + NEDGES;

    const float* g0_w1 = (const float*)d_in[3];
    const float* g0_b1 = (const float*)d_in[4];
    const float* g0_ga = (const float*)d_in[5];
    const float* g0_be = (const float*)d_in[6];
    const float* g0_w2 = (const float*)d_in[7];
    const float* g0_b2 = (const float*)d_in[8];
    const float* g1_w1 = (const float*)d_in[9];
    const float* g1_b1 = (const float*)d_in[10];
    const float* g1_ga = (const float*)d_in[11];
    const float* g1_be = (const float*)d_in[12];
    const float* g1_w2 = (const float*)d_in[13];
    const float* g1_b2 = (const float*)d_in[14];
    const float* g2_w1 = (const float*)d_in[15];
    const float* g2_b1 = (const float*)d_in[16];
    const float* g2_ga = (const float*)d_in[17];
    const float* g2_be = (const float*)d_in[18];
    const float* g2_w2 = (const float*)d_in[19];
    const float* g2_b2 = (const float*)d_in[20];
    const float* fc0_w = (const float*)d_in[21];
    const float* fc0_b = (const float*)d_in[22];
    const float* fc1_w = (const float*)d_in[23];
    const float* fc1_b = (const float*)d_in[24];

    // --- workspace layout (~222 MB) ---
    float* ws = (float*)d_ws;
    const size_t BUF = (size_t)NNODES * 256;
    float* R0 = ws;
    float* R1 = R0 + BUF;
    float* stats = R1 + BUF;                         // 2*256
    float* scsh = stats + 512;                       // 2*256 (scale, shift)
    float* g = scsh + 512;                           // 2048*128 pooled
    float* gh = g + (size_t)NGRAPHS * 128;           // 2048*1024 fc hidden
    int* deg = (int*)(gh + (size_t)NGRAPHS * 1024);  // NNODES
    int* rowptr = deg + NNODES;                      // NNODES+1
    int* cursor = rowptr + NNODES + 4;               // NNODES
    int* adj = cursor + NNODES;                      // NEDGES

    const int MB = (NNODES + 127) / 128;  // 782 row-blocks

    // --- build CSR once ---
    hipMemsetAsync(deg, 0, NNODES * sizeof(int), stream);
    deg_kernel<<<(NEDGES + 255) / 256, 256, 0, stream>>>(dstA, deg);
    scan_kernel<<<1, 1024, 0, stream>>>(deg, rowptr, cursor);
    fill_kernel<<<(NEDGES + 255) / 256, 256, 0, stream>>>(srcA, dstA, cursor, adj);

    // ================= Layer 0 (66 -> 128 -> 128) =================
    // gather at 66 into stride-68 padded buffer (16B-aligned rows for vector staging).
    // Cols 66..67 are garbage but W rows >= Kw=66 read as 0, so they never contribute.
    gather_kernel<66, 2, 68><<<(NNODES * 33 + 255) / 256, 256, 0, stream>>>(x, rowptr, adj, R0,
                                                                            nullptr);
    hipMemsetAsync(stats, 0, 2 * 128 * sizeof(float), stream);
    gemm128x64_kernel<false, false, true><<<dim3(MB, 2), 256, 0, stream>>>(
        R0, g0_w1, g0_b1, nullptr, nullptr, R1, stats, NNODES, 68, 66, 128);
    bnfinal_kernel<<<1, 128, 0, stream>>>(stats, g0_ga, g0_be, scsh, scsh + 128, 128, 1.0f / NNODES);
    gemm128x64_kernel<true, true, false><<<dim3(MB, 2), 256, 0, stream>>>(
        R1, g0_w2, g0_b2, scsh, scsh + 128, R0, nullptr, NNODES, 128, 128, 128);

    // ================= Layer 1 (128 -> 256 -> 256) =================
    gather_kernel<128, 4, 128><<<(NNODES * 32 + 255) / 256, 256, 0, stream>>>(R0, rowptr, adj, R1,
                                                                              nullptr);
    hipMemsetAsync(stats, 0, 2 * 256 * sizeof(float), stream);
    gemm128x64_kernel<false, false, true><<<dim3(MB, 4), 256, 0, stream>>>(
        R1, g1_w1, g1_b1, nullptr, nullptr, R0, stats, NNODES, 128, 128, 256);
    bnfinal_kernel<<<1, 256, 0, stream>>>(stats, g1_ga, g1_be, scsh, scsh + 256, 256, 1.0f / NNODES);
    gemm128x64_kernel<true, true, false><<<dim3(MB, 4), 256, 0, stream>>>(
        R0, g1_w2, g1_b2, scsh, scsh + 256, R1, nullptr, NNODES, 256, 256, 256);

    // ================= Layer 2 (256 -> 128 -> 128), REORDERED =================
    // GINConv linear in x: (x + sum_j x_j) @ W1 + b1 == (x@W1) + sum_j (x@W1)_j + b1.
    gemm128x64_kernel<false, false, false><<<dim3(MB, 2), 256, 0, stream>>>(
        R1, g2_w1, nullptr, nullptr, nullptr, R0, nullptr, NNODES, 256, 256, 128);
    gather_kernel<128, 4, 128><<<(NNODES * 32 + 255) / 256, 256, 0, stream>>>(R0, rowptr, adj, R1,
                                                                              g2_b1);
    hipMemsetAsync(stats, 0, 2 * 128 * sizeof(float), stream);
    bnstats_kernel<128><<<128, 256, 0, stream>>>(R1, stats);
    bnfinal_kernel<<<1, 128, 0, stream>>>(stats, g2_ga, g2_be, scsh, scsh + 128, 128, 1.0f / NNODES);
    gemm128x64_kernel<true, true, false><<<dim3(MB, 2), 256, 0, stream>>>(
        R1, g2_w2, g2_b2, scsh, scsh + 128, R0, nullptr, NNODES, 128, 128, 128);

    // ================= pool + FC head =================
    hipMemsetAsync(g, 0, (size_t)NGRAPHS * 128 * sizeof(float), stream);
    pool_kernel<<<(NNODES * 32 + 255) / 256, 256, 0, stream>>>(R0, batch, g);

    gemm64_kernel<true><<<dim3(NGRAPHS / 64, 1024 / 64), 256, 0, stream>>>(g, fc0_w, fc0_b, gh,
                                                                           NGRAPHS, 128, 1024);
    gemm64_kernel<false><<<dim3(NGRAPHS / 64, 128 / 64), 256, 0, stream>>>(
        gh, fc1_w, fc1_b, (float*)d_out, NGRAPHS, 1024, 128);
}

// Round 6
// 1750.324 us; speedup vs baseline: 5.9851x; 1.1203x over previous
//
#include <hip/hip_runtime.h>

#define NNODES 100000
#define NEDGES 1600000
#define NGRAPHS 2048
#define BN_EPS 1e-5f

// ---------------- CSR build ----------------
__global__ __launch_bounds__(256) void deg_kernel(const int* __restrict__ dstA,
                                                  int* __restrict__ deg) {
    int e = blockIdx.x * 256 + threadIdx.x;
    if (e < NEDGES) atomicAdd(&deg[dstA[e]], 1);
}

// ---- 3-phase parallel exclusive scan of deg -> rowptr/cursor ----
// phase 1: per-block (256-elem) sums
__global__ __launch_bounds__(256) void scan1_kernel(const int* __restrict__ deg,
                                                    int* __restrict__ partials) {
    int b = blockIdx.x;
    int i = b * 256 + threadIdx.x;
    int v = (i < NNODES) ? deg[i] : 0;
    __shared__ int wsum[4];
#pragma unroll
    for (int off = 32; off; off >>= 1) v += __shfl_down(v, off);
    if ((threadIdx.x & 63) == 0) wsum[threadIdx.x >> 6] = v;
    __syncthreads();
    if (threadIdx.x == 0) partials[b] = wsum[0] + wsum[1] + wsum[2] + wsum[3];
}

// phase 2: single small block scans the partials into EXCLUSIVE offsets
__global__ __launch_bounds__(512) void scan2_kernel(int* __restrict__ partials, int nb) {
    __shared__ int s[512];
    int t = threadIdx.x;
    int v = (t < nb) ? partials[t] : 0;
    s[t] = v;
    __syncthreads();
    for (int off = 1; off < 512; off <<= 1) {
        int u = (t >= off) ? s[t - off] : 0;
        __syncthreads();
        s[t] += u;
        __syncthreads();
    }
    if (t < nb) partials[t] = s[t] - v;  // exclusive
}

// phase 3: block-local exclusive scan + block offset -> rowptr & cursor
__global__ __launch_bounds__(256) void scan3_kernel(const int* __restrict__ deg,
                                                    const int* __restrict__ partials,
                                                    int* __restrict__ rowptr,
                                                    int* __restrict__ cursor) {
    int b = blockIdx.x;
    int t = threadIdx.x;
    int i = b * 256 + t;
    __shared__ int s[256];
    int v = (i < NNODES) ? deg[i] : 0;
    s[t] = v;
    __syncthreads();
    for (int off = 1; off < 256; off <<= 1) {
        int u = (t >= off) ? s[t - off] : 0;
        __syncthreads();
        s[t] += u;
        __syncthreads();
    }
    if (i < NNODES) {
        int ex = partials[b] + s[t] - v;
        rowptr[i] = ex;
        cursor[i] = ex;
    }
    if (b == 0 && t == 0) rowptr[NNODES] = NEDGES;  // sum(deg) == NEDGES
}

__global__ __launch_bounds__(256) void fill_kernel(const int* __restrict__ srcA,
                                                   const int* __restrict__ dstA,
                                                   int* __restrict__ cursor,
                                                   int* __restrict__ adj) {
    int e = blockIdx.x * 256 + threadIdx.x;
    if (e < NEDGES) {
        int d = dstA[e];
        int loc = atomicAdd(&cursor[d], 1);
        adj[loc] = srcA[e];
    }
}

// ------- gather aggregation: agg[n] = x[n] + sum_{s in adj[n]} x[s] (+bias) -------
// DIM: input row width (floats). OSTRIDE: output row stride (floats) — may pad.
template <int DIM, int CHUNK, int OSTRIDE>
__global__ __launch_bounds__(256) void gather_kernel(const float* __restrict__ x,
                                                     const int* __restrict__ rowptr,
                                                     const int* __restrict__ adj,
                                                     float* __restrict__ agg,
                                                     const float* __restrict__ bias) {
    constexpr int PE = DIM / CHUNK;
    int gid = blockIdx.x * 256 + threadIdx.x;
    if (gid >= NNODES * PE) return;
    int node = gid / PE;
    int c = gid - node * PE;
    const int beg = rowptr[node];
    const int end = rowptr[node + 1];
    if (CHUNK == 4) {
        const float4* xp = (const float4*)x;
        float4 acc = xp[(size_t)node * PE + c];
        for (int i = beg; i < end; ++i) {
            int s = adj[i];
            float4 v = xp[(size_t)s * PE + c];
            acc.x += v.x;
            acc.y += v.y;
            acc.z += v.z;
            acc.w += v.w;
        }
        if (bias) {
            float4 b = *(const float4*)&bias[c * 4];
            acc.x += b.x; acc.y += b.y; acc.z += b.z; acc.w += b.w;
        }
        *(float4*)&agg[(size_t)node * OSTRIDE + c * 4] = acc;
    } else {
        const float2* xp = (const float2*)x;
        float2 acc = xp[(size_t)node * PE + c];
        for (int i = beg; i < end; ++i) {
            int s = adj[i];
            float2 v = xp[(size_t)s * PE + c];
            acc.x += v.x;
            acc.y += v.y;
        }
        *(float2*)&agg[(size_t)node * OSTRIDE + c * 2] = acc;
    }
}

// ---------------- BN stats (standalone, used once for L2) ----------------
template <int N>
__global__ __launch_bounds__(256) void bnstats_kernel(const float* __restrict__ h,
                                                      float* __restrict__ sums) {
    constexpr int SHIFT = (N == 128) ? 7 : 8;
    int t = blockIdx.x * 256 + threadIdx.x;
    int col = t & (N - 1);
    int slice = t >> SHIFT;
    float s = 0.f, s2 = 0.f;
    for (int r = slice; r < NNODES; r += 256) {
        float v = h[(size_t)r * N + col];
        s += v;
        s2 += v * v;
    }
    atomicAdd(&sums[col], s);
    atomicAdd(&sums[N + col], s2);
}

__global__ void bnfinal_kernel(const float* __restrict__ sums, const float* __restrict__ gamma,
                               const float* __restrict__ beta, float* __restrict__ scale,
                               float* __restrict__ shift, int N, float invM) {
    int c = blockIdx.x * blockDim.x + threadIdx.x;
    if (c < N) {
        float mean = sums[c] * invM;
        float var = sums[N + c] * invM - mean * mean;
        float sc = gamma[c] * rsqrtf(var + BN_EPS);
        scale[c] = sc;
        shift[c] = beta[c] - mean * sc;
    }
}

__device__ __forceinline__ void fma44(float (&cc)[4][4], const float4& a, const float4& b) {
    cc[0][0] += a.x * b.x; cc[0][1] += a.x * b.y; cc[0][2] += a.x * b.z; cc[0][3] += a.x * b.w;
    cc[1][0] += a.y * b.x; cc[1][1] += a.y * b.y; cc[1][2] += a.y * b.z; cc[1][3] += a.y * b.w;
    cc[2][0] += a.z * b.x; cc[2][1] += a.z * b.y; cc[2][2] += a.z * b.z; cc[2][3] += a.z * b.w;
    cc[3][0] += a.w * b.x; cc[3][1] += a.w * b.y; cc[3][2] += a.w * b.z; cc[3][3] += a.w * b.w;
}

// ---------------- 128x64 tile fp32 GEMM, 8x4/thread (2 row-quadrants of 4x4) ----------
// A: M x K row-major (K = padded stride & loop bound, 16B-aligned rows => K%4==0).
// W: Kw x N row-major (Kw = real K; rows >= Kw read as 0).
template <bool BNRELU_A, bool RELU_OUT, bool FUSE_STATS>
__global__ __launch_bounds__(256) void gemm128x64_kernel(
    const float* __restrict__ A, const float* __restrict__ W, const float* __restrict__ bias,
    const float* __restrict__ scale, const float* __restrict__ shift, float* __restrict__ C,
    float* __restrict__ stats, int M, int K, int Kw, int N) {
    __shared__ __align__(16) float As[16][132];  // [k][m], 132 stride (16B-aligned rows)
    __shared__ __align__(16) float Bs[16][64];   // [k][n]
    __shared__ float sstat[128];                 // 64 sum + 64 sumsq
    const int tid = threadIdx.x;
    const int tx = tid & 15;   // n quad: tx*4
    const int ty = tid >> 4;   // m quad: ty*4 (+64)
    const int m0 = blockIdx.x * 128;
    const int n0 = blockIdx.y * 64;

    if (FUSE_STATS && tid < 128) sstat[tid] = 0.f;  // synced by first k-loop barrier

    float c[2][4][4] = {};

    for (int k0 = 0; k0 < K; k0 += 16) {
        // ---- stage A tile (128 rows x 16 k) transposed into As[k][m] ----
#pragma unroll
        for (int i = 0; i < 2; ++i) {
            int lin4 = tid + i * 256;  // [0,512)
            int row = lin4 >> 2;       // 0..127
            int kq = lin4 & 3;         // k-quad
            int gm = m0 + row;
            float4 v = make_float4(0.f, 0.f, 0.f, 0.f);
            if (gm < M) v = *(const float4*)&A[(size_t)gm * K + k0 + kq * 4];
            if (BNRELU_A) {
                int gk = k0 + kq * 4;
                v.x = fmaxf(v.x * scale[gk + 0] + shift[gk + 0], 0.f);
                v.y = fmaxf(v.y * scale[gk + 1] + shift[gk + 1], 0.f);
                v.z = fmaxf(v.z * scale[gk + 2] + shift[gk + 2], 0.f);
                v.w = fmaxf(v.w * scale[gk + 3] + shift[gk + 3], 0.f);
            }
            As[kq * 4 + 0][row] = v.x;
            As[kq * 4 + 1][row] = v.y;
            As[kq * 4 + 2][row] = v.z;
            As[kq * 4 + 3][row] = v.w;
        }
        // ---- stage W tile (16 k x 64 n): 1 float4 per thread; guard by Kw ----
        {
            int kr = tid >> 4;  // 0..15
            int nq = tid & 15;  // 0..15
            int gk = k0 + kr;
            float4 v = make_float4(0.f, 0.f, 0.f, 0.f);
            if (gk < Kw) v = *(const float4*)&W[(size_t)gk * N + n0 + nq * 4];
            *(float4*)&Bs[kr][nq * 4] = v;
        }
        __syncthreads();
        // ---- inner product with explicit next-kk prefetch ----
        float4 a0 = *(const float4*)&As[0][ty * 4];
        float4 a1 = *(const float4*)&As[0][64 + ty * 4];
        float4 b = *(const float4*)&Bs[0][tx * 4];
#pragma unroll
        for (int kk = 0; kk < 16; ++kk) {
            float4 na0, na1, nb;
            if (kk < 15) {
                na0 = *(const float4*)&As[kk + 1][ty * 4];
                na1 = *(const float4*)&As[kk + 1][64 + ty * 4];
                nb = *(const float4*)&Bs[kk + 1][tx * 4];
            }
            fma44(c[0], a0, b);
            fma44(c[1], a1, b);
            if (kk < 15) {
                a0 = na0;
                a1 = na1;
                b = nb;
            }
        }
        __syncthreads();
    }

    // ---- epilogue: bias (+relu) store, optional fused column stats ----
    float s_sum[4] = {}, s_sq[4] = {};
    const bool hasb = (bias != nullptr);
    const int gn = n0 + tx * 4;
    float4 bv = make_float4(0.f, 0.f, 0.f, 0.f);
    if (hasb) bv = *(const float4*)&bias[gn];
#pragma unroll
    for (int qa = 0; qa < 2; ++qa) {
#pragma unroll
        for (int i = 0; i < 4; ++i) {
            int gm = m0 + qa * 64 + ty * 4 + i;
            if (gm >= M) continue;
            float4 v;
            v.x = c[qa][i][0] + bv.x;
            v.y = c[qa][i][1] + bv.y;
            v.z = c[qa][i][2] + bv.z;
            v.w = c[qa][i][3] + bv.w;
            if (RELU_OUT) {
                v.x = fmaxf(v.x, 0.f); v.y = fmaxf(v.y, 0.f);
                v.z = fmaxf(v.z, 0.f); v.w = fmaxf(v.w, 0.f);
            }
            *(float4*)&C[(size_t)gm * N + gn] = v;
            if (FUSE_STATS) {
                s_sum[0] += v.x; s_sq[0] += v.x * v.x;
                s_sum[1] += v.y; s_sq[1] += v.y * v.y;
                s_sum[2] += v.z; s_sq[2] += v.z * v.z;
                s_sum[3] += v.w; s_sq[3] += v.w * v.w;
            }
        }
    }
    if (FUSE_STATS) {
#pragma unroll
        for (int j = 0; j < 4; ++j) {
            int cl = tx * 4 + j;
            atomicAdd(&sstat[cl], s_sum[j]);
            atomicAdd(&sstat[64 + cl], s_sq[j]);
        }
        __syncthreads();
        if (tid < 64) {
            atomicAdd(&stats[n0 + tid], sstat[tid]);
            atomicAdd(&stats[N + n0 + tid], sstat[64 + tid]);
        }
    }
}

// ---------------- 64x64 tile fp32 GEMM (fc0/fc1 head, tiny) ----------------
template <bool RELU_OUT>
__global__ __launch_bounds__(256) void gemm64_kernel(const float* __restrict__ A,
                                                     const float* __restrict__ W,
                                                     const float* __restrict__ bias,
                                                     float* __restrict__ C, int M, int K, int N) {
    __shared__ __align__(16) float As[16][68];
    __shared__ __align__(16) float Bs[16][64];
    const int tid = threadIdx.x;
    const int tx = tid & 15;
    const int ty = tid >> 4;
    const int m0 = blockIdx.x * 64;
    const int n0 = blockIdx.y * 64;

    float c[4][4] = {};

    for (int k0 = 0; k0 < K; k0 += 16) {
#pragma unroll
        for (int i = 0; i < 4; ++i) {
            int lin = tid + i * 256;
            int m = lin >> 4;
            int k = lin & 15;
            int gm = m0 + m;
            int gk = k0 + k;
            float v = 0.f;
            if (gm < M && gk < K) v = A[(size_t)gm * K + gk];
            As[k][m] = v;
        }
#pragma unroll
        for (int i = 0; i < 4; ++i) {
            int lin = tid + i * 256;
            int k = lin >> 6;
            int n = lin & 63;
            int gk = k0 + k;
            float v = 0.f;
            if (gk < K) v = W[(size_t)gk * N + n0 + n];
            Bs[k][n] = v;
        }
        __syncthreads();
#pragma unroll
        for (int kk = 0; kk < 16; ++kk) {
            float4 a = *(const float4*)&As[kk][ty * 4];
            float4 b = *(const float4*)&Bs[kk][tx * 4];
            c[0][0] += a.x * b.x; c[0][1] += a.x * b.y; c[0][2] += a.x * b.z; c[0][3] += a.x * b.w;
            c[1][0] += a.y * b.x; c[1][1] += a.y * b.y; c[1][2] += a.y * b.z; c[1][3] += a.y * b.w;
            c[2][0] += a.z * b.x; c[2][1] += a.z * b.y; c[2][2] += a.z * b.z; c[2][3] += a.z * b.w;
            c[3][0] += a.w * b.x; c[3][1] += a.w * b.y; c[3][2] += a.w * b.z; c[3][3] += a.w * b.w;
        }
        __syncthreads();
    }

#pragma unroll
    for (int i = 0; i < 4; ++i) {
        int gm = m0 + ty * 4 + i;
        if (gm >= M) continue;
#pragma unroll
        for (int j = 0; j < 4; ++j) {
            int gn = n0 + tx * 4 + j;
            float v = c[i][j] + bias[gn];
            if (RELU_OUT) v = fmaxf(v, 0.f);
            C[(size_t)gm * N + gn] = v;
        }
    }
}

// ---------------- global add pool ----------------
__global__ __launch_bounds__(256) void pool_kernel(const float* __restrict__ h,
                                                   const int* __restrict__ batch,
                                                   float* __restrict__ g) {
    int gid = blockIdx.x * 256 + threadIdx.x;
    if (gid >= NNODES * 32) return;
    int node = gid >> 5;
    int c4 = gid & 31;
    int b = batch[node];
    float4 v = *(const float4*)&h[(size_t)node * 128 + c4 * 4];
    float* gp = &g[(size_t)b * 128 + c4 * 4];
    atomicAdd(gp + 0, v.x);
    atomicAdd(gp + 1, v.y);
    atomicAdd(gp + 2, v.z);
    atomicAdd(gp + 3, v.w);
}

extern "C" void kernel_launch(void* const* d_in, const int* in_sizes, int n_in, void* d_out,
                              int out_size, void* d_ws, size_t ws_size, hipStream_t stream) {
    const float* x = (const float*)d_in[0];
    const int* ei = (const int*)d_in[1];
    const int* batch = (const int*)d_in[2];
    const int* srcA = ei;
    const int* dstA = ei + NEDGES;

    const float* g0_w1 = (const float*)d_in[3];
    const float* g0_b1 = (const float*)d_in[4];
    const float* g0_ga = (const float*)d_in[5];
    const float* g0_be = (const float*)d_in[6];
    const float* g0_w2 = (const float*)d_in[7];
    const float* g0_b2 = (const float*)d_in[8];
    const float* g1_w1 = (const float*)d_in[9];
    const float* g1_b1 = (const float*)d_in[10];
    const float* g1_ga = (const float*)d_in[11];
    const float* g1_be = (const float*)d_in[12];
    const float* g1_w2 = (const float*)d_in[13];
    const float* g1_b2 = (const float*)d_in[14];
    const float* g2_w1 = (const float*)d_in[15];
    const float* g2_b1 = (const float*)d_in[16];
    const float* g2_ga = (const float*)d_in[17];
    const float* g2_be = (const float*)d_in[18];
    const float* g2_w2 = (const float*)d_in[19];
    const float* g2_b2 = (const float*)d_in[20];
    const float* fc0_w = (const float*)d_in[21];
    const float* fc0_b = (const float*)d_in[22];
    const float* fc1_w = (const float*)d_in[23];
    const float* fc1_b = (const float*)d_in[24];

    // --- workspace layout (~222 MB) ---
    float* ws = (float*)d_ws;
    const size_t BUF = (size_t)NNODES * 256;
    float* R0 = ws;
    float* R1 = R0 + BUF;
    float* stats = R1 + BUF;                         // 2*256
    float* scsh = stats + 512;                       // 2*256 (scale, shift)
    float* g = scsh + 512;                           // 2048*128 pooled
    float* gh = g + (size_t)NGRAPHS * 128;           // 2048*1024 fc hidden
    int* deg = (int*)(gh + (size_t)NGRAPHS * 1024);  // NNODES
    int* rowptr = deg + NNODES;                      // NNODES+1
    int* cursor = rowptr + NNODES + 4;               // NNODES
    int* adj = cursor + NNODES;                      // NEDGES
    int* partials = adj + NEDGES;                    // ceil(NNODES/256) = 391

    const int MB = (NNODES + 127) / 128;   // 782 row-blocks
    const int NB = (NNODES + 255) / 256;   // 391 scan blocks

    // --- build CSR once (parallel 3-phase scan; R5: single-block scan was 230us @ 0.15% occ) ---
    hipMemsetAsync(deg, 0, NNODES * sizeof(int), stream);
    deg_kernel<<<(NEDGES + 255) / 256, 256, 0, stream>>>(dstA, deg);
    scan1_kernel<<<NB, 256, 0, stream>>>(deg, partials);
    scan2_kernel<<<1, 512, 0, stream>>>(partials, NB);
    scan3_kernel<<<NB, 256, 0, stream>>>(deg, partials, rowptr, cursor);
    fill_kernel<<<(NEDGES + 255) / 256, 256, 0, stream>>>(srcA, dstA, cursor, adj);

    // ================= Layer 0 (66 -> 128 -> 128) =================
    gather_kernel<66, 2, 68><<<(NNODES * 33 + 255) / 256, 256, 0, stream>>>(x, rowptr, adj, R0,
                                                                            nullptr);
    hipMemsetAsync(stats, 0, 2 * 128 * sizeof(float), stream);
    gemm128x64_kernel<false, false, true><<<dim3(MB, 2), 256, 0, stream>>>(
        R0, g0_w1, g0_b1, nullptr, nullptr, R1, stats, NNODES, 68, 66, 128);
    bnfinal_kernel<<<1, 128, 0, stream>>>(stats, g0_ga, g0_be, scsh, scsh + 128, 128, 1.0f / NNODES);
    gemm128x64_kernel<true, true, false><<<dim3(MB, 2), 256, 0, stream>>>(
        R1, g0_w2, g0_b2, scsh, scsh + 128, R0, nullptr, NNODES, 128, 128, 128);

    // ================= Layer 1 (128 -> 256 -> 256) =================
    gather_kernel<128, 4, 128><<<(NNODES * 32 + 255) / 256, 256, 0, stream>>>(R0, rowptr, adj, R1,
                                                                              nullptr);
    hipMemsetAsync(stats, 0, 2 * 256 * sizeof(float), stream);
    gemm128x64_kernel<false, false, true><<<dim3(MB, 4), 256, 0, stream>>>(
        R1, g1_w1, g1_b1, nullptr, nullptr, R0, stats, NNODES, 128, 128, 256);
    bnfinal_kernel<<<1, 256, 0, stream>>>(stats, g1_ga, g1_be, scsh, scsh + 256, 256, 1.0f / NNODES);
    gemm128x64_kernel<true, true, false><<<dim3(MB, 4), 256, 0, stream>>>(
        R0, g1_w2, g1_b2, scsh, scsh + 256, R1, nullptr, NNODES, 256, 256, 256);

    // ================= Layer 2 (256 -> 128 -> 128), REORDERED =================
    // GINConv linear in x: (x + sum_j x_j) @ W1 + b1 == (x@W1) + sum_j (x@W1)_j + b1.
    gemm128x64_kernel<false, false, false><<<dim3(MB, 2), 256, 0, stream>>>(
        R1, g2_w1, nullptr, nullptr, nullptr, R0, nullptr, NNODES, 256, 256, 128);
    gather_kernel<128, 4, 128><<<(NNODES * 32 + 255) / 256, 256, 0, stream>>>(R0, rowptr, adj, R1,
                                                                              g2_b1);
    hipMemsetAsync(stats, 0, 2 * 128 * sizeof(float), stream);
    bnstats_kernel<128><<<128, 256, 0, stream>>>(R1, stats);
    bnfinal_kernel<<<1, 128, 0, stream>>>(stats, g2_ga, g2_be, scsh, scsh + 128, 128, 1.0f / NNODES);
    gemm128x64_kernel<true, true, false><<<dim3(MB, 2), 256, 0, stream>>>(
        R1, g2_w2, g2_b2, scsh, scsh + 128, R0, nullptr, NNODES, 128, 128, 128);

    // ================= pool + FC head =================
    hipMemsetAsync(g, 0, (size_t)NGRAPHS * 128 * sizeof(float), stream);
    pool_kernel<<<(NNODES * 32 + 255) / 256, 256, 0, stream>>>(R0, batch, g);

    gemm64_kernel<true><<<dim3(NGRAPHS / 64, 1024 / 64), 256, 0, stream>>>(g, fc0_w, fc0_b, gh,
                                                                           NGRAPHS, 128, 1024);
    gemm64_kernel<false><<<dim3(NGRAPHS / 64, 128 / 64), 256, 0, stream>>>(
        gh, fc1_w, fc1_b, (float*)d_out, NGRAPHS, 1024, 128);
}

// Round 7
// 1552.449 us; speedup vs baseline: 6.7480x; 1.1275x over previous
//
#include <hip/hip_runtime.h>

#define NNODES 100000
#define NEDGES 1600000
#define NGRAPHS 2048
#define BN_EPS 1e-5f

// ---------------- CSR build ----------------
__global__ __launch_bounds__(256) void deg_kernel(const int* __restrict__ dstA,
                                                  int* __restrict__ deg) {
    int e = blockIdx.x * 256 + threadIdx.x;
    if (e < NEDGES) atomicAdd(&deg[dstA[e]], 1);
}

// ---- 3-phase parallel exclusive scan of deg -> rowptr/cursor ----
__global__ __launch_bounds__(256) void scan1_kernel(const int* __restrict__ deg,
                                                    int* __restrict__ partials) {
    int b = blockIdx.x;
    int i = b * 256 + threadIdx.x;
    int v = (i < NNODES) ? deg[i] : 0;
    __shared__ int wsum[4];
#pragma unroll
    for (int off = 32; off; off >>= 1) v += __shfl_down(v, off);
    if ((threadIdx.x & 63) == 0) wsum[threadIdx.x >> 6] = v;
    __syncthreads();
    if (threadIdx.x == 0) partials[b] = wsum[0] + wsum[1] + wsum[2] + wsum[3];
}

__global__ __launch_bounds__(512) void scan2_kernel(int* __restrict__ partials, int nb) {
    __shared__ int s[512];
    int t = threadIdx.x;
    int v = (t < nb) ? partials[t] : 0;
    s[t] = v;
    __syncthreads();
    for (int off = 1; off < 512; off <<= 1) {
        int u = (t >= off) ? s[t - off] : 0;
        __syncthreads();
        s[t] += u;
        __syncthreads();
    }
    if (t < nb) partials[t] = s[t] - v;  // exclusive
}

__global__ __launch_bounds__(256) void scan3_kernel(const int* __restrict__ deg,
                                                    const int* __restrict__ partials,
                                                    int* __restrict__ rowptr,
                                                    int* __restrict__ cursor) {
    int b = blockIdx.x;
    int t = threadIdx.x;
    int i = b * 256 + t;
    __shared__ int s[256];
    int v = (i < NNODES) ? deg[i] : 0;
    s[t] = v;
    __syncthreads();
    for (int off = 1; off < 256; off <<= 1) {
        int u = (t >= off) ? s[t - off] : 0;
        __syncthreads();
        s[t] += u;
        __syncthreads();
    }
    if (i < NNODES) {
        int ex = partials[b] + s[t] - v;
        rowptr[i] = ex;
        cursor[i] = ex;
    }
    if (b == 0 && t == 0) rowptr[NNODES] = NEDGES;  // sum(deg) == NEDGES
}

__global__ __launch_bounds__(256) void fill_kernel(const int* __restrict__ srcA,
                                                   const int* __restrict__ dstA,
                                                   int* __restrict__ cursor,
                                                   int* __restrict__ adj) {
    int e = blockIdx.x * 256 + threadIdx.x;
    if (e < NEDGES) {
        int d = dstA[e];
        int loc = atomicAdd(&cursor[d], 1);
        adj[loc] = srcA[e];
    }
}

// ---- graph boundaries from sorted batch: gstart[g] = first node of graph g ----
__global__ __launch_bounds__(256) void gbound_kernel(const int* __restrict__ batch,
                                                     int* __restrict__ gstart) {
    int i = blockIdx.x * 256 + threadIdx.x;
    if (i >= NNODES) return;
    int b = batch[i];
    int bp = (i == 0) ? -1 : batch[i - 1];
    for (int g = bp + 1; g <= b; ++g) gstart[g] = i;
    if (i == NNODES - 1)
        for (int g = b + 1; g <= NGRAPHS; ++g) gstart[g] = NNODES;
}

// ------- gather aggregation: agg[n] = x[n] + sum_{s in adj[n]} x[s] (+bias) -------
template <int DIM, int CHUNK, int OSTRIDE>
__global__ __launch_bounds__(256) void gather_kernel(const float* __restrict__ x,
                                                     const int* __restrict__ rowptr,
                                                     const int* __restrict__ adj,
                                                     float* __restrict__ agg,
                                                     const float* __restrict__ bias) {
    constexpr int PE = DIM / CHUNK;
    int gid = blockIdx.x * 256 + threadIdx.x;
    if (gid >= NNODES * PE) return;
    int node = gid / PE;
    int c = gid - node * PE;
    const int beg = rowptr[node];
    const int end = rowptr[node + 1];
    if (CHUNK == 4) {
        const float4* xp = (const float4*)x;
        float4 acc = xp[(size_t)node * PE + c];
        for (int i = beg; i < end; ++i) {
            int s = adj[i];
            float4 v = xp[(size_t)s * PE + c];
            acc.x += v.x;
            acc.y += v.y;
            acc.z += v.z;
            acc.w += v.w;
        }
        if (bias) {
            float4 b = *(const float4*)&bias[c * 4];
            acc.x += b.x; acc.y += b.y; acc.z += b.z; acc.w += b.w;
        }
        *(float4*)&agg[(size_t)node * OSTRIDE + c * 4] = acc;
    } else {
        const float2* xp = (const float2*)x;
        float2 acc = xp[(size_t)node * PE + c];
        for (int i = beg; i < end; ++i) {
            int s = adj[i];
            float2 v = xp[(size_t)s * PE + c];
            acc.x += v.x;
            acc.y += v.y;
        }
        *(float2*)&agg[(size_t)node * OSTRIDE + c * 2] = acc;
    }
}

// ---------------- BN stats (standalone, used once for L2) ----------------
template <int N>
__global__ __launch_bounds__(256) void bnstats_kernel(const float* __restrict__ h,
                                                      float* __restrict__ sums) {
    constexpr int SHIFT = (N == 128) ? 7 : 8;
    int t = blockIdx.x * 256 + threadIdx.x;
    int col = t & (N - 1);
    int slice = t >> SHIFT;
    float s = 0.f, s2 = 0.f;
    for (int r = slice; r < NNODES; r += 256) {
        float v = h[(size_t)r * N + col];
        s += v;
        s2 += v * v;
    }
    atomicAdd(&sums[col], s);
    atomicAdd(&sums[N + col], s2);
}

__global__ void bnfinal_kernel(const float* __restrict__ sums, const float* __restrict__ gamma,
                               const float* __restrict__ beta, float* __restrict__ scale,
                               float* __restrict__ shift, int N, float invM) {
    int c = blockIdx.x * blockDim.x + threadIdx.x;
    if (c < N) {
        float mean = sums[c] * invM;
        float var = sums[N + c] * invM - mean * mean;
        float sc = gamma[c] * rsqrtf(var + BN_EPS);
        scale[c] = sc;
        shift[c] = beta[c] - mean * sc;
    }
}

__device__ __forceinline__ void fma44(float (&cc)[4][4], const float4& a, const float4& b) {
    cc[0][0] += a.x * b.x; cc[0][1] += a.x * b.y; cc[0][2] += a.x * b.z; cc[0][3] += a.x * b.w;
    cc[1][0] += a.y * b.x; cc[1][1] += a.y * b.y; cc[1][2] += a.y * b.z; cc[1][3] += a.y * b.w;
    cc[2][0] += a.z * b.x; cc[2][1] += a.z * b.y; cc[2][2] += a.z * b.z; cc[2][3] += a.z * b.w;
    cc[3][0] += a.w * b.x; cc[3][1] += a.w * b.y; cc[3][2] += a.w * b.z; cc[3][3] += a.w * b.w;
}

// ---------------- 128x64 tile fp32 GEMM, 8x4/thread ----------
template <bool BNRELU_A, bool RELU_OUT, bool FUSE_STATS>
__global__ __launch_bounds__(256) void gemm128x64_kernel(
    const float* __restrict__ A, const float* __restrict__ W, const float* __restrict__ bias,
    const float* __restrict__ scale, const float* __restrict__ shift, float* __restrict__ C,
    float* __restrict__ stats, int M, int K, int Kw, int N) {
    __shared__ __align__(16) float As[16][132];
    __shared__ __align__(16) float Bs[16][64];
    __shared__ float sstat[128];
    const int tid = threadIdx.x;
    const int tx = tid & 15;
    const int ty = tid >> 4;
    const int m0 = blockIdx.x * 128;
    const int n0 = blockIdx.y * 64;

    if (FUSE_STATS && tid < 128) sstat[tid] = 0.f;

    float c[2][4][4] = {};

    for (int k0 = 0; k0 < K; k0 += 16) {
#pragma unroll
        for (int i = 0; i < 2; ++i) {
            int lin4 = tid + i * 256;
            int row = lin4 >> 2;
            int kq = lin4 & 3;
            int gm = m0 + row;
            float4 v = make_float4(0.f, 0.f, 0.f, 0.f);
            if (gm < M) v = *(const float4*)&A[(size_t)gm * K + k0 + kq * 4];
            if (BNRELU_A) {
                int gk = k0 + kq * 4;
                v.x = fmaxf(v.x * scale[gk + 0] + shift[gk + 0], 0.f);
                v.y = fmaxf(v.y * scale[gk + 1] + shift[gk + 1], 0.f);
                v.z = fmaxf(v.z * scale[gk + 2] + shift[gk + 2], 0.f);
                v.w = fmaxf(v.w * scale[gk + 3] + shift[gk + 3], 0.f);
            }
            As[kq * 4 + 0][row] = v.x;
            As[kq * 4 + 1][row] = v.y;
            As[kq * 4 + 2][row] = v.z;
            As[kq * 4 + 3][row] = v.w;
        }
        {
            int kr = tid >> 4;
            int nq = tid & 15;
            int gk = k0 + kr;
            float4 v = make_float4(0.f, 0.f, 0.f, 0.f);
            if (gk < Kw) v = *(const float4*)&W[(size_t)gk * N + n0 + nq * 4];
            *(float4*)&Bs[kr][nq * 4] = v;
        }
        __syncthreads();
        float4 a0 = *(const float4*)&As[0][ty * 4];
        float4 a1 = *(const float4*)&As[0][64 + ty * 4];
        float4 b = *(const float4*)&Bs[0][tx * 4];
#pragma unroll
        for (int kk = 0; kk < 16; ++kk) {
            float4 na0, na1, nb;
            if (kk < 15) {
                na0 = *(const float4*)&As[kk + 1][ty * 4];
                na1 = *(const float4*)&As[kk + 1][64 + ty * 4];
                nb = *(const float4*)&Bs[kk + 1][tx * 4];
            }
            fma44(c[0], a0, b);
            fma44(c[1], a1, b);
            if (kk < 15) {
                a0 = na0;
                a1 = na1;
                b = nb;
            }
        }
        __syncthreads();
    }

    float s_sum[4] = {}, s_sq[4] = {};
    const bool hasb = (bias != nullptr);
    const int gn = n0 + tx * 4;
    float4 bv = make_float4(0.f, 0.f, 0.f, 0.f);
    if (hasb) bv = *(const float4*)&bias[gn];
#pragma unroll
    for (int qa = 0; qa < 2; ++qa) {
#pragma unroll
        for (int i = 0; i < 4; ++i) {
            int gm = m0 + qa * 64 + ty * 4 + i;
            if (gm >= M) continue;
            float4 v;
            v.x = c[qa][i][0] + bv.x;
            v.y = c[qa][i][1] + bv.y;
            v.z = c[qa][i][2] + bv.z;
            v.w = c[qa][i][3] + bv.w;
            if (RELU_OUT) {
                v.x = fmaxf(v.x, 0.f); v.y = fmaxf(v.y, 0.f);
                v.z = fmaxf(v.z, 0.f); v.w = fmaxf(v.w, 0.f);
            }
            *(float4*)&C[(size_t)gm * N + gn] = v;
            if (FUSE_STATS) {
                s_sum[0] += v.x; s_sq[0] += v.x * v.x;
                s_sum[1] += v.y; s_sq[1] += v.y * v.y;
                s_sum[2] += v.z; s_sq[2] += v.z * v.z;
                s_sum[3] += v.w; s_sq[3] += v.w * v.w;
            }
        }
    }
    if (FUSE_STATS) {
#pragma unroll
        for (int j = 0; j < 4; ++j) {
            int cl = tx * 4 + j;
            atomicAdd(&sstat[cl], s_sum[j]);
            atomicAdd(&sstat[64 + cl], s_sq[j]);
        }
        __syncthreads();
        if (tid < 64) {
            atomicAdd(&stats[n0 + tid], sstat[tid]);
            atomicAdd(&stats[N + n0 + tid], sstat[64 + tid]);
        }
    }
}

// ---------------- 64x64 tile fp32 GEMM (fc0/fc1 head) ----------------
template <bool RELU_OUT>
__global__ __launch_bounds__(256) void gemm64_kernel(const float* __restrict__ A,
                                                     const float* __restrict__ W,
                                                     const float* __restrict__ bias,
                                                     float* __restrict__ C, int M, int K, int N) {
    __shared__ __align__(16) float As[16][68];
    __shared__ __align__(16) float Bs[16][64];
    const int tid = threadIdx.x;
    const int tx = tid & 15;
    const int ty = tid >> 4;
    const int m0 = blockIdx.x * 64;
    const int n0 = blockIdx.y * 64;

    float c[4][4] = {};

    for (int k0 = 0; k0 < K; k0 += 16) {
#pragma unroll
        for (int i = 0; i < 4; ++i) {
            int lin = tid + i * 256;
            int m = lin >> 4;
            int k = lin & 15;
            int gm = m0 + m;
            int gk = k0 + k;
            float v = 0.f;
            if (gm < M && gk < K) v = A[(size_t)gm * K + gk];
            As[k][m] = v;
        }
#pragma unroll
        for (int i = 0; i < 4; ++i) {
            int lin = tid + i * 256;
            int k = lin >> 6;
            int n = lin & 63;
            int gk = k0 + k;
            float v = 0.f;
            if (gk < K) v = W[(size_t)gk * N + n0 + n];
            Bs[k][n] = v;
        }
        __syncthreads();
#pragma unroll
        for (int kk = 0; kk < 16; ++kk) {
            float4 a = *(const float4*)&As[kk][ty * 4];
            float4 b = *(const float4*)&Bs[kk][tx * 4];
            c[0][0] += a.x * b.x; c[0][1] += a.x * b.y; c[0][2] += a.x * b.z; c[0][3] += a.x * b.w;
            c[1][0] += a.y * b.x; c[1][1] += a.y * b.y; c[1][2] += a.y * b.z; c[1][3] += a.y * b.w;
            c[2][0] += a.z * b.x; c[2][1] += a.z * b.y; c[2][2] += a.z * b.z; c[2][3] += a.z * b.w;
            c[3][0] += a.w * b.x; c[3][1] += a.w * b.y; c[3][2] += a.w * b.z; c[3][3] += a.w * b.w;
        }
        __syncthreads();
    }

#pragma unroll
    for (int i = 0; i < 4; ++i) {
        int gm = m0 + ty * 4 + i;
        if (gm >= M) continue;
#pragma unroll
        for (int j = 0; j < 4; ++j) {
            int gn = n0 + tx * 4 + j;
            float v = c[i][j] + bias[gn];
            if (RELU_OUT) v = fmaxf(v, 0.f);
            C[(size_t)gm * N + gn] = v;
        }
    }
}

// ---- segmented pool over sorted batch: g[gr] = sum rows [gstart[gr], gstart[gr+1]) ----
__global__ __launch_bounds__(128) void pool_seg_kernel(const float* __restrict__ h,
                                                       const int* __restrict__ gstart,
                                                       float* __restrict__ g) {
    int gr = blockIdx.x;
    int t = threadIdx.x;  // column 0..127
    int beg = gstart[gr];
    int end = gstart[gr + 1];
    float acc = 0.f;
    for (int r = beg; r < end; ++r) acc += h[(size_t)r * 128 + t];
    g[(size_t)gr * 128 + t] = acc;
}

extern "C" void kernel_launch(void* const* d_in, const int* in_sizes, int n_in, void* d_out,
                              int out_size, void* d_ws, size_t ws_size, hipStream_t stream) {
    const float* x = (const float*)d_in[0];
    const int* ei = (const int*)d_in[1];
    const int* batch = (const int*)d_in[2];
    const int* srcA = ei;
    const int* dstA = ei + NEDGES;

    const float* g0_w1 = (const float*)d_in[3];
    const float* g0_b1 = (const float*)d_in[4];
    const float* g0_ga = (const float*)d_in[5];
    const float* g0_be = (const float*)d_in[6];
    const float* g0_w2 = (const float*)d_in[7];
    const float* g0_b2 = (const float*)d_in[8];
    const float* g1_w1 = (const float*)d_in[9];
    const float* g1_b1 = (const float*)d_in[10];
    const float* g1_ga = (const float*)d_in[11];
    const float* g1_be = (const float*)d_in[12];
    const float* g1_w2 = (const float*)d_in[13];
    const float* g1_b2 = (const float*)d_in[14];
    const float* g2_w1 = (const float*)d_in[15];
    const float* g2_b1 = (const float*)d_in[16];
    const float* g2_ga = (const float*)d_in[17];
    const float* g2_be = (const float*)d_in[18];
    const float* g2_w2 = (const float*)d_in[19];
    const float* g2_b2 = (const float*)d_in[20];
    const float* fc0_w = (const float*)d_in[21];
    const float* fc0_b = (const float*)d_in[22];
    const float* fc1_w = (const float*)d_in[23];
    const float* fc1_b = (const float*)d_in[24];

    // --- workspace layout (~222 MB) ---
    float* ws = (float*)d_ws;
    const size_t BUF = (size_t)NNODES * 256;
    float* R0 = ws;
    float* R1 = R0 + BUF;
    float* stats = R1 + BUF;                         // 2*256
    float* scsh = stats + 512;                       // 2*256 (scale, shift)
    float* g = scsh + 512;                           // 2048*128 pooled
    float* gh = g + (size_t)NGRAPHS * 128;           // 2048*1024 fc hidden
    int* deg = (int*)(gh + (size_t)NGRAPHS * 1024);  // NNODES
    int* rowptr = deg + NNODES;                      // NNODES+1
    int* cursor = rowptr + NNODES + 4;               // NNODES
    int* adj = cursor + NNODES;                      // NEDGES
    int* partials = adj + NEDGES;                    // 391
    int* gstart = partials + 512;                    // NGRAPHS+1

    const int MB = (NNODES + 127) / 128;  // 782 row-blocks
    const int NB = (NNODES + 255) / 256;  // 391 scan blocks

    // --- build CSR + graph bounds once ---
    hipMemsetAsync(deg, 0, NNODES * sizeof(int), stream);
    deg_kernel<<<(NEDGES + 255) / 256, 256, 0, stream>>>(dstA, deg);
    scan1_kernel<<<NB, 256, 0, stream>>>(deg, partials);
    scan2_kernel<<<1, 512, 0, stream>>>(partials, NB);
    scan3_kernel<<<NB, 256, 0, stream>>>(deg, partials, rowptr, cursor);
    fill_kernel<<<(NEDGES + 255) / 256, 256, 0, stream>>>(srcA, dstA, cursor, adj);
    gbound_kernel<<<NB, 256, 0, stream>>>(batch, gstart);

    // ================= Layer 0 (66 -> 128 -> 128) =================
    gather_kernel<66, 2, 68><<<(NNODES * 33 + 255) / 256, 256, 0, stream>>>(x, rowptr, adj, R0,
                                                                            nullptr);
    hipMemsetAsync(stats, 0, 2 * 128 * sizeof(float), stream);
    gemm128x64_kernel<false, false, true><<<dim3(MB, 2), 256, 0, stream>>>(
        R0, g0_w1, g0_b1, nullptr, nullptr, R1, stats, NNODES, 68, 66, 128);
    bnfinal_kernel<<<1, 128, 0, stream>>>(stats, g0_ga, g0_be, scsh, scsh + 128, 128, 1.0f / NNODES);
    gemm128x64_kernel<true, true, false><<<dim3(MB, 2), 256, 0, stream>>>(
        R1, g0_w2, g0_b2, scsh, scsh + 128, R0, nullptr, NNODES, 128, 128, 128);

    // ================= Layer 1 (128 -> 256 -> 256) =================
    gather_kernel<128, 4, 128><<<(NNODES * 32 + 255) / 256, 256, 0, stream>>>(R0, rowptr, adj, R1,
                                                                              nullptr);
    hipMemsetAsync(stats, 0, 2 * 256 * sizeof(float), stream);
    gemm128x64_kernel<false, false, true><<<dim3(MB, 4), 256, 0, stream>>>(
        R1, g1_w1, g1_b1, nullptr, nullptr, R0, stats, NNODES, 128, 128, 256);
    bnfinal_kernel<<<1, 256, 0, stream>>>(stats, g1_ga, g1_be, scsh, scsh + 256, 256, 1.0f / NNODES);
    gemm128x64_kernel<true, true, false><<<dim3(MB, 4), 256, 0, stream>>>(
        R0, g1_w2, g1_b2, scsh, scsh + 256, R1, nullptr, NNODES, 256, 256, 256);

    // ================= Layer 2 (256 -> 128 -> 128), REORDERED =================
    gemm128x64_kernel<false, false, false><<<dim3(MB, 2), 256, 0, stream>>>(
        R1, g2_w1, nullptr, nullptr, nullptr, R0, nullptr, NNODES, 256, 256, 128);
    gather_kernel<128, 4, 128><<<(NNODES * 32 + 255) / 256, 256, 0, stream>>>(R0, rowptr, adj, R1,
                                                                              g2_b1);
    hipMemsetAsync(stats, 0, 2 * 128 * sizeof(float), stream);
    bnstats_kernel<128><<<128, 256, 0, stream>>>(R1, stats);
    bnfinal_kernel<<<1, 128, 0, stream>>>(stats, g2_ga, g2_be, scsh, scsh + 128, 128, 1.0f / NNODES);
    gemm128x64_kernel<true, true, false><<<dim3(MB, 2), 256, 0, stream>>>(
        R1, g2_w2, g2_b2, scsh, scsh + 128, R0, nullptr, NNODES, 128, 128, 128);

    // ================= pool (segmented, no atomics) + FC head =================
    pool_seg_kernel<<<NGRAPHS, 128, 0, stream>>>(R0, gstart, g);

    gemm64_kernel<true><<<dim3(NGRAPHS / 64, 1024 / 64), 256, 0, stream>>>(g, fc0_w, fc0_b, gh,
                                                                           NGRAPHS, 128, 1024);
    gemm64_kernel<false><<<dim3(NGRAPHS / 64, 128 / 64), 256, 0, stream>>>(
        gh, fc1_w, fc1_b, (float*)d_out, NGRAPHS, 1024, 128);
}